// Round 11
// baseline (260.914 us; speedup 1.0000x reference)
//
#include <hip/hip_runtime.h>
#include <hip/hip_bf16.h>

#define D 256
#define BM 64
#define BMF 16    // fused tile rows
#define LDA 264   // LDS k-stride in bf16 elems (528 B rows)
#define LDK 72    // fallback-path pad

typedef __attribute__((ext_vector_type(8))) __bf16 bf16x8;
typedef __attribute__((ext_vector_type(4))) float f32x4;

__device__ __forceinline__ float bf2f(unsigned short u) {
    union { unsigned int i; float f; } c; c.i = ((unsigned int)u) << 16; return c.f;
}
__device__ __forceinline__ float bf2f_lo(unsigned int u) {
    union { unsigned int i; float f; } c; c.i = u << 16; return c.f;
}
__device__ __forceinline__ float bf2f_hi(unsigned int u) {
    union { unsigned int i; float f; } c; c.i = u & 0xffff0000u; return c.f;
}
__device__ __forceinline__ unsigned short f2bf(float f) {
    __hip_bfloat16 h = __float2bfloat16(f);
    return *reinterpret_cast<unsigned short*>(&h);
}
__device__ __forceinline__ unsigned int pack2(float lo, float hi) {
    return (unsigned int)f2bf(lo) | ((unsigned int)f2bf(hi) << 16);
}

// ======================= FAST PATH =======================

// blocks [0,nbF): feat fp32->bf16 ; [nbF,nbF+512): W->Wt[c][k] ; rest: edge histogram.
// deg must be zeroed before this kernel.
__global__ void k_prep(const float* __restrict__ uf, const float* __restrict__ itf,
                       const float* __restrict__ Wu, const float* __restrict__ Wi,
                       unsigned short* __restrict__ feat_bf,
                       unsigned short* __restrict__ Wt_u, unsigned short* __restrict__ Wt_i,
                       const int* __restrict__ iu_e, int Eiu,
                       const int* __restrict__ ui_e, int Eui,
                       int* __restrict__ deg, int NU,
                       size_t nfU, size_t nfTot, int nbF) {
    int b = blockIdx.x;
    if (b < nbF) {
        size_t base = ((size_t)b * 256 + threadIdx.x) * 8;
        if (base < nfTot) {
            const float* s = (base < nfU) ? (uf + base) : (itf + (base - nfU));
            float4 f0 = *(const float4*)s;
            float4 f1 = *(const float4*)(s + 4);
            ushort4 o0, o1;
            o0.x = f2bf(f0.x); o0.y = f2bf(f0.y); o0.z = f2bf(f0.z); o0.w = f2bf(f0.w);
            o1.x = f2bf(f1.x); o1.y = f2bf(f1.y); o1.z = f2bf(f1.z); o1.w = f2bf(f1.w);
            ((ushort4*)(feat_bf + base))[0] = o0;
            ((ushort4*)(feat_bf + base))[1] = o1;
        }
    } else if (b < nbF + 512) {
        int b2 = b - nbF;
        const float* W = (b2 < 256) ? Wu : Wi;
        unsigned short* Wt = (b2 < 256) ? Wt_u : Wt_i;
        int k = b2 & 255;
        int c = threadIdx.x;
        Wt[(size_t)c * 256 + k] = f2bf(W[(size_t)k * 256 + c]);
    } else {
        int e = (b - nbF - 512) * 256 + threadIdx.x;
        if (e < Eiu) {
            atomicAdd(&deg[iu_e[Eiu + e]], 1);
        } else if (e < Eiu + Eui) {
            int e2 = e - Eiu;
            atomicAdd(&deg[NU + ui_e[Eui + e2]], 1);
        }
    }
}

__global__ void k_scan_block(const int* __restrict__ deg, int N,
                             int* __restrict__ rs, int* __restrict__ bsums) {
    __shared__ int s[1024];
    int base = blockIdx.x * 1024;
    int t = threadIdx.x;
    int v = (base + t < N) ? deg[base + t] : 0;
    s[t] = v;
    __syncthreads();
    for (int off = 1; off < 1024; off <<= 1) {
        int add = (t >= off) ? s[t - off] : 0;
        __syncthreads();
        s[t] += add;
        __syncthreads();
    }
    if (base + t < N) rs[base + t + 1] = s[t];
    if (t == 1023) bsums[blockIdx.x] = s[1023];
}

__global__ void k_scan_sums(int* __restrict__ bsums, int nb) {
    __shared__ int s[1024];
    int t = threadIdx.x;
    int v = (t < nb) ? bsums[t] : 0;
    s[t] = v;
    __syncthreads();
    for (int off = 1; off < 1024; off <<= 1) {
        int add = (t >= off) ? s[t - off] : 0;
        __syncthreads();
        s[t] += add;
        __syncthreads();
    }
    if (t < nb) bsums[t] = s[t] - v;
}

__global__ void k_finalize(int N, int* __restrict__ rs, int* __restrict__ cur,
                           const int* __restrict__ bsums) {
    int i = blockIdx.x * blockDim.x + threadIdx.x;
    if (i < N) {
        int v = rs[i + 1] + bsums[i >> 10];
        rs[i + 1] = v;
        cur[i + 1] = v;
    }
    if (i == 0) { rs[0] = 0; cur[0] = 0; }
}

__global__ void k_fill2(const int* __restrict__ iu_e, int Eiu,
                        const int* __restrict__ ui_e, int Eui,
                        int* __restrict__ cur, int NU,
                        int* __restrict__ csr) {
    int e = blockIdx.x * blockDim.x + threadIdx.x;
    if (e < Eiu) {
        int d = iu_e[Eiu + e];
        int p = atomicAdd(&cur[d], 1);
        csr[p] = iu_e[e];
    } else if (e < Eiu + Eui) {
        int e2 = e - Eiu;
        int d = ui_e[Eui + e2];
        int p = atomicAdd(&cur[NU + d], 1);
        csr[p] = ui_e[e2];
    }
}

// ---- FUSED gather+GEMM+LN, msg2-geometry gather.
// 512 threads = 8 waves; tile = 16 rows. Each wave gathers 2 rows (one per
// 32-lane half, 4-unrolled = 8 loads in flight) into the LDS A-tile; one
// barrier; 8 waves GEMM 16x256 (wave w owns cols [w*32,w*32+32)); LN; store.
__launch_bounds__(512)
__global__ void k_fused2(const unsigned short* __restrict__ uf_bf,
                         const unsigned short* __restrict__ if_bf,
                         const unsigned short* __restrict__ Wt_u,
                         const unsigned short* __restrict__ Wt_i,
                         const int* __restrict__ rs, const int* __restrict__ csr,
                         const float* __restrict__ bu, const float* __restrict__ bi,
                         const float* __restrict__ gamma, const float* __restrict__ beta,
                         int NU, int NI, int nbU, float* __restrict__ out) {
    __shared__ __align__(16) __hip_bfloat16 As[BMF][LDA];  // 8448 B
    __shared__ float red_s[BMF][8];                         // 512 B
    __shared__ float red_q[BMF][8];                         // 512 B

    int b = blockIdx.x;
    bool isU = b < nbU;
    const unsigned short* srcT = isU ? if_bf : uf_bf;
    const unsigned short* tgtT = isU ? uf_bf : if_bf;
    const unsigned short* Wt   = isU ? Wt_u : Wt_i;
    const float* bias          = isU ? bu : bi;
    float* Y                   = isU ? out : out + (size_t)NU * D;
    int N                      = isU ? NU : NI;
    int row0 = (isU ? b : b - nbU) * BMF;
    int wvBase = (isU ? 0 : NU) + row0;

    int t = threadIdx.x;       // 0..511
    int w = t >> 6;            // wave 0..7
    int lane = t & 63;
    int half = lane >> 5;
    int hl = lane & 31;
    int l15 = lane & 15;
    int l4 = lane >> 4;

    // ---- Phase A: gather 2 rows per wave (msg2 geometry) into As
    {
        int lrow = w * 2 + half;
        int grow = row0 + lrow;
        if (grow < N) {
            int wv = wvBase + lrow;
            int s0 = rs[wv], s1 = rs[wv + 1];
            float a0[8] = {}, a1[8] = {}, a2[8] = {}, a3[8] = {};
            int i = s0;
            for (; i + 4 <= s1; i += 4) {
                int e0 = csr[i], e1 = csr[i + 1], e2 = csr[i + 2], e3 = csr[i + 3];
                uint4 r0 = ((const uint4*)(srcT + (size_t)e0 * D))[hl];
                uint4 r1 = ((const uint4*)(srcT + (size_t)e1 * D))[hl];
                uint4 r2 = ((const uint4*)(srcT + (size_t)e2 * D))[hl];
                uint4 r3 = ((const uint4*)(srcT + (size_t)e3 * D))[hl];
                a0[0] += bf2f_lo(r0.x); a0[1] += bf2f_hi(r0.x); a0[2] += bf2f_lo(r0.y); a0[3] += bf2f_hi(r0.y);
                a0[4] += bf2f_lo(r0.z); a0[5] += bf2f_hi(r0.z); a0[6] += bf2f_lo(r0.w); a0[7] += bf2f_hi(r0.w);
                a1[0] += bf2f_lo(r1.x); a1[1] += bf2f_hi(r1.x); a1[2] += bf2f_lo(r1.y); a1[3] += bf2f_hi(r1.y);
                a1[4] += bf2f_lo(r1.z); a1[5] += bf2f_hi(r1.z); a1[6] += bf2f_lo(r1.w); a1[7] += bf2f_hi(r1.w);
                a2[0] += bf2f_lo(r2.x); a2[1] += bf2f_hi(r2.x); a2[2] += bf2f_lo(r2.y); a2[3] += bf2f_hi(r2.y);
                a2[4] += bf2f_lo(r2.z); a2[5] += bf2f_hi(r2.z); a2[6] += bf2f_lo(r2.w); a2[7] += bf2f_hi(r2.w);
                a3[0] += bf2f_lo(r3.x); a3[1] += bf2f_hi(r3.x); a3[2] += bf2f_lo(r3.y); a3[3] += bf2f_hi(r3.y);
                a3[4] += bf2f_lo(r3.z); a3[5] += bf2f_hi(r3.z); a3[6] += bf2f_lo(r3.w); a3[7] += bf2f_hi(r3.w);
            }
            for (; i < s1; ++i) {
                int e0 = csr[i];
                uint4 r0 = ((const uint4*)(srcT + (size_t)e0 * D))[hl];
                a0[0] += bf2f_lo(r0.x); a0[1] += bf2f_hi(r0.x); a0[2] += bf2f_lo(r0.y); a0[3] += bf2f_hi(r0.y);
                a0[4] += bf2f_lo(r0.z); a0[5] += bf2f_hi(r0.z); a0[6] += bf2f_lo(r0.w); a0[7] += bf2f_hi(r0.w);
            }
            int cnt = s1 - s0;
            float inv = 1.0f / (float)(cnt > 0 ? cnt : 1);
            uint4 tv = ((const uint4*)(tgtT + (size_t)grow * D))[hl];
            float x0 = bf2f_lo(tv.x) + (a0[0] + a1[0] + a2[0] + a3[0]) * inv;
            float x1 = bf2f_hi(tv.x) + (a0[1] + a1[1] + a2[1] + a3[1]) * inv;
            float x2 = bf2f_lo(tv.y) + (a0[2] + a1[2] + a2[2] + a3[2]) * inv;
            float x3 = bf2f_hi(tv.y) + (a0[3] + a1[3] + a2[3] + a3[3]) * inv;
            float x4 = bf2f_lo(tv.z) + (a0[4] + a1[4] + a2[4] + a3[4]) * inv;
            float x5 = bf2f_hi(tv.z) + (a0[5] + a1[5] + a2[5] + a3[5]) * inv;
            float x6 = bf2f_lo(tv.w) + (a0[6] + a1[6] + a2[6] + a3[6]) * inv;
            float x7 = bf2f_hi(tv.w) + (a0[7] + a1[7] + a2[7] + a3[7]) * inv;
            uint4 o;
            o.x = pack2(x0, x1); o.y = pack2(x2, x3); o.z = pack2(x4, x5); o.w = pack2(x6, x7);
            *(uint4*)&As[lrow][hl * 8] = o;
        } else {
            uint4 z = {0, 0, 0, 0};
            *(uint4*)&As[lrow][hl * 8] = z;
        }
    }

    __syncthreads();

    // ---- Phase B: GEMM 16x256. Wave w owns cols [w*32, w*32+32); B from L2.
    const uint4* Bg = (const uint4*)Wt;   // Wt[col][k]: uint4 index = col*32 + k/8
    f32x4 acc[2];
    f32x4 zero = {0.f, 0.f, 0.f, 0.f};
    acc[0] = zero; acc[1] = zero;
    #pragma unroll
    for (int ks8 = 0; ks8 < 8; ++ks8) {
        bf16x8 af = *(const bf16x8*)&As[l15][ks8 * 32 + l4 * 8];
        #pragma unroll
        for (int fc = 0; fc < 2; ++fc) {
            uint4 bq = Bg[(size_t)(w * 32 + fc * 16 + l15) * 32 + ks8 * 4 + l4];
            acc[fc] = __builtin_amdgcn_mfma_f32_16x16x32_bf16(
                af, *(bf16x8*)&bq, acc[fc], 0, 0, 0);
        }
    }

    // ---- epilogue: bias + relu + per-row partial reduce (this wave's 32 cols)
    float bias_c[2], gam_c[2], bet_c[2];
    #pragma unroll
    for (int fc = 0; fc < 2; ++fc) {
        int col = w * 32 + fc * 16 + l15;
        bias_c[fc] = bias[col];
        gam_c[fc]  = gamma[col];
        bet_c[fc]  = beta[col];
    }

    #pragma unroll
    for (int r = 0; r < 4; ++r) {
        int row = l4 * 4 + r;
        float s = 0.f, q = 0.f;
        #pragma unroll
        for (int fc = 0; fc < 2; ++fc) {
            float v = acc[fc][r] + bias_c[fc];
            v = fmaxf(v, 0.f);
            acc[fc][r] = v;
            s += v;
            q += v * v;
        }
        #pragma unroll
        for (int m = 1; m < 16; m <<= 1) {
            s += __shfl_xor(s, m);
            q += __shfl_xor(q, m);
        }
        if (l15 == 0) { red_s[row][w] = s; red_q[row][w] = q; }
    }
    __syncthreads();

    #pragma unroll
    for (int r = 0; r < 4; ++r) {
        int row = l4 * 4 + r;
        int grow = row0 + row;
        if (grow >= N) continue;
        float s = red_s[row][0] + red_s[row][1] + red_s[row][2] + red_s[row][3]
                + red_s[row][4] + red_s[row][5] + red_s[row][6] + red_s[row][7];
        float q = red_q[row][0] + red_q[row][1] + red_q[row][2] + red_q[row][3]
                + red_q[row][4] + red_q[row][5] + red_q[row][6] + red_q[row][7];
        float mu  = s * (1.0f / 256.0f);
        float var = q * (1.0f / 256.0f) - mu * mu;
        float rstd = rsqrtf(var + 1e-5f);
        #pragma unroll
        for (int fc = 0; fc < 2; ++fc) {
            int col = w * 32 + fc * 16 + l15;
            Y[(size_t)grow * D + col] = (acc[fc][r] - mu) * rstd * gam_c[fc] + bet_c[fc];
        }
    }
}

// ======================= FALLBACK PATH (R2, small-ws) =======================

__global__ void k_hist(const int* __restrict__ dst, int E, int* __restrict__ deg) {
    int e = blockIdx.x * blockDim.x + threadIdx.x;
    if (e < E) atomicAdd(&deg[dst[e]], 1);
}

__global__ void k_finalize_rs(int N, int* __restrict__ rs, const int* __restrict__ bsums) {
    int i = blockIdx.x * blockDim.x + threadIdx.x;
    if (i < N) rs[i + 1] += bsums[i >> 10];
    if (i == 0) rs[0] = 0;
}

__global__ void k_fill(const int* __restrict__ src, const int* __restrict__ dst, int E,
                       const int* __restrict__ rs, int* __restrict__ cursor,
                       int* __restrict__ csr) {
    int e = blockIdx.x * blockDim.x + threadIdx.x;
    if (e < E) {
        int d = dst[e];
        int p = atomicAdd(&cursor[d], 1);
        csr[rs[d] + p] = src[e];
    }
}

__global__ void k_msg_x(const float* __restrict__ srcf, const float* __restrict__ tgtf,
                        const int* __restrict__ rs, const int* __restrict__ csr,
                        int N, float* __restrict__ xout) {
    int wave = (blockIdx.x * blockDim.x + threadIdx.x) >> 6;
    int lane = threadIdx.x & 63;
    if (wave >= N) return;
    int s0 = rs[wave], s1 = rs[wave + 1];
    float4 acc = make_float4(0.f, 0.f, 0.f, 0.f);
    for (int i = s0; i < s1; i++) {
        int s = csr[i];
        float4 f = *(const float4*)&srcf[(size_t)s * D + lane * 4];
        acc.x += f.x; acc.y += f.y; acc.z += f.z; acc.w += f.w;
    }
    int cnt = s1 - s0;
    float inv = 1.0f / (float)(cnt > 0 ? cnt : 1);
    float4 t = *(const float4*)&tgtf[(size_t)wave * D + lane * 4];
    float4 x;
    x.x = t.x + acc.x * inv;
    x.y = t.y + acc.y * inv;
    x.z = t.z + acc.z * inv;
    x.w = t.w + acc.w * inv;
    *(float4*)&xout[(size_t)wave * D + lane * 4] = x;
}

__global__ void k_wcvt(const float* __restrict__ W0, const float* __restrict__ W1,
                       __hip_bfloat16* __restrict__ Wt0, __hip_bfloat16* __restrict__ Wt1) {
    int b = blockIdx.x;
    const float* W = (b < 256) ? W0 : W1;
    __hip_bfloat16* Wt = (b < 256) ? Wt0 : Wt1;
    int k = b & 255;
    int c = threadIdx.x;
    Wt[(size_t)c * 256 + k] = __float2bfloat16(W[(size_t)k * 256 + c]);
}

__launch_bounds__(256)
__global__ void k_gemm_mfma_ln(const float* __restrict__ X,
                               const __hip_bfloat16* __restrict__ Wt,
                               const float* __restrict__ bias,
                               const float* __restrict__ gamma,
                               const float* __restrict__ beta,
                               int N, float* __restrict__ Y) {
    __shared__ __hip_bfloat16 As[BM][LDK];
    __shared__ __hip_bfloat16 Bs[D][LDK];
    __shared__ float red_s[BM][4];
    __shared__ float red_q[BM][4];

    int t = threadIdx.x;
    int lane = t & 63;
    int w = t >> 6;
    int l15 = lane & 15;
    int l4 = lane >> 4;
    int row0 = blockIdx.x * BM;

    f32x4 acc[4][4];
    f32x4 zero = {0.f, 0.f, 0.f, 0.f};
    #pragma unroll
    for (int fr = 0; fr < 4; fr++)
        #pragma unroll
        for (int fc = 0; fc < 4; fc++)
            acc[fr][fc] = zero;

    for (int k0 = 0; k0 < D; k0 += 64) {
        {
            int i = t >> 2;
            int kq = (t & 3) * 16;
            int r = row0 + i;
            float4 f[4];
            if (r < N) {
                const float4* p = (const float4*)&X[(size_t)r * D + k0 + kq];
                f[0] = p[0]; f[1] = p[1]; f[2] = p[2]; f[3] = p[3];
            } else {
                float4 z4 = make_float4(0.f, 0.f, 0.f, 0.f);
                f[0] = z4; f[1] = z4; f[2] = z4; f[3] = z4;
            }
            __hip_bfloat16 vb[16];
            #pragma unroll
            for (int q = 0; q < 4; q++) {
                vb[q * 4 + 0] = __float2bfloat16(f[q].x);
                vb[q * 4 + 1] = __float2bfloat16(f[q].y);
                vb[q * 4 + 2] = __float2bfloat16(f[q].z);
                vb[q * 4 + 3] = __float2bfloat16(f[q].w);
            }
            *(uint4*)&As[i][kq]     = *(uint4*)&vb[0];
            *(uint4*)&As[i][kq + 8] = *(uint4*)&vb[8];
        }
        #pragma unroll
        for (int pass = 0; pass < 4; pass++) {
            int c = pass * 64 + (t >> 2);
            int kq = (t & 3) * 16;
            const uint4* p = (const uint4*)&Wt[(size_t)c * D + k0 + kq];
            uint4 b0 = p[0], b1 = p[1];
            *(uint4*)&Bs[c][kq]     = b0;
            *(uint4*)&Bs[c][kq + 8] = b1;
        }
        __syncthreads();

        #pragma unroll
        for (int ks = 0; ks < 2; ks++) {
            bf16x8 af[4], bg[4];
            #pragma unroll
            for (int fr = 0; fr < 4; fr++)
                af[fr] = *(const bf16x8*)&As[fr * 16 + l15][ks * 32 + l4 * 8];
            #pragma unroll
            for (int fc = 0; fc < 4; fc++)
                bg[fc] = *(const bf16x8*)&Bs[w * 64 + fc * 16 + l15][ks * 32 + l4 * 8];
            #pragma unroll
            for (int fr = 0; fr < 4; fr++)
                #pragma unroll
                for (int fc = 0; fc < 4; fc++)
                    acc[fr][fc] = __builtin_amdgcn_mfma_f32_16x16x32_bf16(
                        af[fr], bg[fc], acc[fr][fc], 0, 0, 0);
        }
        __syncthreads();
    }

    float bias_c[4], gam_c[4], bet_c[4];
    #pragma unroll
    for (int fc = 0; fc < 4; fc++) {
        int col = w * 64 + fc * 16 + l15;
        bias_c[fc] = bias[col];
        gam_c[fc]  = gamma[col];
        bet_c[fc]  = beta[col];
    }

    #pragma unroll
    for (int fr = 0; fr < 4; fr++) {
        #pragma unroll
        for (int r = 0; r < 4; r++) {
            int row = fr * 16 + l4 * 4 + r;
            float s = 0.f, q = 0.f;
            #pragma unroll
            for (int fc = 0; fc < 4; fc++) {
                float v = acc[fr][fc][r] + bias_c[fc];
                v = fmaxf(v, 0.f);
                acc[fr][fc][r] = v;
                s += v;
                q += v * v;
            }
            #pragma unroll
            for (int m = 1; m < 16; m <<= 1) {
                s += __shfl_xor(s, m);
                q += __shfl_xor(q, m);
            }
            if (l15 == 0) { red_s[row][w] = s; red_q[row][w] = q; }
        }
    }
    __syncthreads();

    #pragma unroll
    for (int fr = 0; fr < 4; fr++) {
        #pragma unroll
        for (int r = 0; r < 4; r++) {
            int row = fr * 16 + l4 * 4 + r;
            int grow = row0 + row;
            if (grow >= N) continue;
            float s = red_s[row][0] + red_s[row][1] + red_s[row][2] + red_s[row][3];
            float q = red_q[row][0] + red_q[row][1] + red_q[row][2] + red_q[row][3];
            float mu  = s * (1.0f / 256.0f);
            float var = q * (1.0f / 256.0f) - mu * mu;
            float rstd = rsqrtf(var + 1e-5f);
            #pragma unroll
            for (int fc = 0; fc < 4; fc++) {
                int col = w * 64 + fc * 16 + l15;
                Y[(size_t)grow * D + col] = (acc[fr][fc][r] - mu) * rstd * gam_c[fc] + bet_c[fc];
            }
        }
    }
}

// ======================= launch =======================

extern "C" void kernel_launch(void* const* d_in, const int* in_sizes, int n_in,
                              void* d_out, int out_size, void* d_ws, size_t ws_size,
                              hipStream_t stream) {
    const float* uf    = (const float*)d_in[0];
    const float* itf   = (const float*)d_in[1];
    const int*   ui_e  = (const int*)d_in[2];   // [2, Eui] user->item
    const int*   iu_e  = (const int*)d_in[3];   // [2, Eiu] item->user
    const float* Wu    = (const float*)d_in[4];
    const float* bu    = (const float*)d_in[5];
    const float* Wi    = (const float*)d_in[6];
    const float* bi    = (const float*)d_in[7];
    const float* gamma = (const float*)d_in[8];
    const float* beta  = (const float*)d_in[9];

    int NU  = in_sizes[0] / D;
    int NI  = in_sizes[1] / D;
    int Eui = in_sizes[2] / 2;
    int Eiu = in_sizes[3] / 2;
    int Nmax = NU > NI ? NU : NI;
    int Ntot = NU + NI;
    int Etot = Eiu + Eui;

    float* out   = (float*)d_out;
    size_t nfU = (size_t)NU * D;
    size_t nfI = (size_t)NI * D;
    size_t nfTot = nfU + nfI;

    // fast-path ws layout (no x buffers)
    unsigned short* uf_bf = (unsigned short*)d_ws;     // nfU
    unsigned short* if_bf = uf_bf + nfU;               // nfI
    unsigned short* Wt_u2 = if_bf + nfI;               // 65536
    unsigned short* Wt_i2 = Wt_u2 + 65536;             // 65536
    int* deg2  = (int*)(Wt_i2 + 65536);                // Ntot
    int* rs2   = deg2 + Ntot;                          // Ntot+1
    int* cur2  = rs2 + Ntot + 1;                       // Ntot+1
    int* bsums = cur2 + Ntot + 1;                      // 1024
    int* csr2  = bsums + 1024;                         // Etot
    size_t needed = (size_t)((char*)(csr2 + Etot) - (char*)d_ws);

    if (ws_size >= needed) {
        int nbF = (int)((nfTot + 2047) / 2048);
        int nbH = (Etot + 255) / 256;
        hipMemsetAsync(deg2, 0, (size_t)Ntot * sizeof(int), stream);
        k_prep<<<nbF + 512 + nbH, 256, 0, stream>>>(uf, itf, Wu, Wi, uf_bf, Wt_u2, Wt_i2,
                                                    iu_e, Eiu, ui_e, Eui, deg2, NU,
                                                    nfU, nfTot, nbF);
        int nb = (Ntot + 1023) / 1024;
        k_scan_block<<<nb, 1024, 0, stream>>>(deg2, Ntot, rs2, bsums);
        k_scan_sums<<<1, 1024, 0, stream>>>(bsums, nb);
        k_finalize<<<(Ntot + 255) / 256, 256, 0, stream>>>(Ntot, rs2, cur2, bsums);
        k_fill2<<<nbH, 256, 0, stream>>>(iu_e, Eiu, ui_e, Eui, cur2, NU, csr2);
        int nbU = (NU + BMF - 1) / BMF;
        int nbI = (NI + BMF - 1) / BMF;
        k_fused2<<<nbU + nbI, 512, 0, stream>>>(uf_bf, if_bf, Wt_u2, Wt_i2, rs2, csr2,
                                                bu, bi, gamma, beta, NU, NI, nbU, out);
        return;
    }

    // ---------- fallback: R2 path (needs ~2.2 MB ws) ----------
    float* u_out = out;
    float* i_out = out + nfU;
    __hip_bfloat16* Wt_u = (__hip_bfloat16*)d_ws;
    __hip_bfloat16* Wt_i = Wt_u + 256 * 256;
    int* deg    = (int*)(Wt_i + 256 * 256);
    int* rs     = deg + Nmax;
    int* bs     = rs + Nmax + 1;
    int* cursor = bs + 1024;
    int* csr    = cursor + Nmax;

    k_wcvt<<<512, 256, 0, stream>>>(Wu, Wi, Wt_u, Wt_i);

    auto run_side = [&](const float* srcf, const float* tgtf, const int* edges, int E,
                        int N, const __hip_bfloat16* Wt, const float* bias, float* y) {
        const int* esrc = edges;
        const int* edst = edges + E;
        hipMemsetAsync(deg, 0, (size_t)N * sizeof(int), stream);
        hipMemsetAsync(cursor, 0, (size_t)N * sizeof(int), stream);
        k_hist<<<(E + 255) / 256, 256, 0, stream>>>(edst, E, deg);
        int nb = (N + 1023) / 1024;
        k_scan_block<<<nb, 1024, 0, stream>>>(deg, N, rs, bs);
        k_scan_sums<<<1, 1024, 0, stream>>>(bs, nb);
        k_finalize_rs<<<(N + 255) / 256, 256, 0, stream>>>(N, rs, bs);
        k_fill<<<(E + 255) / 256, 256, 0, stream>>>(esrc, edst, E, rs, cursor, csr);
        k_msg_x<<<(N + 3) / 4, 256, 0, stream>>>(srcf, tgtf, rs, csr, N, y);
        k_gemm_mfma_ln<<<(N + BM - 1) / BM, 256, 0, stream>>>(y, Wt, bias, gamma, beta, N, y);
    };

    run_side(itf, uf, iu_e, Eiu, NU, Wt_u, bu, u_out);
    run_side(uf, itf, ui_e, Eui, NI, Wt_i, bi, i_out);
}

// Round 12
// 238.518 us; speedup vs baseline: 1.0939x; 1.0939x over previous
//
#include <hip/hip_runtime.h>
#include <hip/hip_bf16.h>

#define D 256
#define BM 64
#define BM2 32    // gemm tile rows
#define LDA 264   // LDS k-stride in bf16 elems (528 B rows)
#define LDK 72    // fallback-path pad

typedef __attribute__((ext_vector_type(8))) __bf16 bf16x8;
typedef __attribute__((ext_vector_type(4))) float f32x4;

__device__ __forceinline__ float bf2f(unsigned short u) {
    union { unsigned int i; float f; } c; c.i = ((unsigned int)u) << 16; return c.f;
}
__device__ __forceinline__ float bf2f_lo(unsigned int u) {
    union { unsigned int i; float f; } c; c.i = u << 16; return c.f;
}
__device__ __forceinline__ float bf2f_hi(unsigned int u) {
    union { unsigned int i; float f; } c; c.i = u & 0xffff0000u; return c.f;
}
__device__ __forceinline__ unsigned short f2bf(float f) {
    __hip_bfloat16 h = __float2bfloat16(f);
    return *reinterpret_cast<unsigned short*>(&h);
}
__device__ __forceinline__ unsigned int pack2(float lo, float hi) {
    return (unsigned int)f2bf(lo) | ((unsigned int)f2bf(hi) << 16);
}

// ======================= shared device bodies (fast path) =======================

// msg2 body: one 32-lane half-wave handles one target row of a side.
__device__ __forceinline__ void msg_pair_body(
    const unsigned short* __restrict__ src, const unsigned short* __restrict__ tgt,
    const int* __restrict__ rs, const int* __restrict__ csr,
    unsigned short* __restrict__ xo, int rsBase, int N, int pair, int lane) {
    int half = lane >> 5;
    int hl   = lane & 31;
    int w = pair * 2 + half;
    if (w >= N) return;
    int wv = rsBase + w;
    int s0 = rs[wv], s1 = rs[wv + 1];
    float a0[8] = {}, a1[8] = {}, a2[8] = {}, a3[8] = {};
    int i = s0;
    for (; i + 4 <= s1; i += 4) {
        int e0 = csr[i], e1 = csr[i + 1], e2 = csr[i + 2], e3 = csr[i + 3];
        uint4 r0 = ((const uint4*)(src + (size_t)e0 * D))[hl];
        uint4 r1 = ((const uint4*)(src + (size_t)e1 * D))[hl];
        uint4 r2 = ((const uint4*)(src + (size_t)e2 * D))[hl];
        uint4 r3 = ((const uint4*)(src + (size_t)e3 * D))[hl];
        a0[0] += bf2f_lo(r0.x); a0[1] += bf2f_hi(r0.x); a0[2] += bf2f_lo(r0.y); a0[3] += bf2f_hi(r0.y);
        a0[4] += bf2f_lo(r0.z); a0[5] += bf2f_hi(r0.z); a0[6] += bf2f_lo(r0.w); a0[7] += bf2f_hi(r0.w);
        a1[0] += bf2f_lo(r1.x); a1[1] += bf2f_hi(r1.x); a1[2] += bf2f_lo(r1.y); a1[3] += bf2f_hi(r1.y);
        a1[4] += bf2f_lo(r1.z); a1[5] += bf2f_hi(r1.z); a1[6] += bf2f_lo(r1.w); a1[7] += bf2f_hi(r1.w);
        a2[0] += bf2f_lo(r2.x); a2[1] += bf2f_hi(r2.x); a2[2] += bf2f_lo(r2.y); a2[3] += bf2f_hi(r2.y);
        a2[4] += bf2f_lo(r2.z); a2[5] += bf2f_hi(r2.z); a2[6] += bf2f_lo(r2.w); a2[7] += bf2f_hi(r2.w);
        a3[0] += bf2f_lo(r3.x); a3[1] += bf2f_hi(r3.x); a3[2] += bf2f_lo(r3.y); a3[3] += bf2f_hi(r3.y);
        a3[4] += bf2f_lo(r3.z); a3[5] += bf2f_hi(r3.z); a3[6] += bf2f_lo(r3.w); a3[7] += bf2f_hi(r3.w);
    }
    for (; i < s1; ++i) {
        int e0 = csr[i];
        uint4 r0 = ((const uint4*)(src + (size_t)e0 * D))[hl];
        a0[0] += bf2f_lo(r0.x); a0[1] += bf2f_hi(r0.x); a0[2] += bf2f_lo(r0.y); a0[3] += bf2f_hi(r0.y);
        a0[4] += bf2f_lo(r0.z); a0[5] += bf2f_hi(r0.z); a0[6] += bf2f_lo(r0.w); a0[7] += bf2f_hi(r0.w);
    }
    int cnt = s1 - s0;
    float inv = 1.0f / (float)(cnt > 0 ? cnt : 1);
    uint4 tv = ((const uint4*)(tgt + (size_t)w * D))[hl];
    float x0 = bf2f_lo(tv.x) + (a0[0] + a1[0] + a2[0] + a3[0]) * inv;
    float x1 = bf2f_hi(tv.x) + (a0[1] + a1[1] + a2[1] + a3[1]) * inv;
    float x2 = bf2f_lo(tv.y) + (a0[2] + a1[2] + a2[2] + a3[2]) * inv;
    float x3 = bf2f_hi(tv.y) + (a0[3] + a1[3] + a2[3] + a3[3]) * inv;
    float x4 = bf2f_lo(tv.z) + (a0[4] + a1[4] + a2[4] + a3[4]) * inv;
    float x5 = bf2f_hi(tv.z) + (a0[5] + a1[5] + a2[5] + a3[5]) * inv;
    float x6 = bf2f_lo(tv.w) + (a0[6] + a1[6] + a2[6] + a3[6]) * inv;
    float x7 = bf2f_hi(tv.w) + (a0[7] + a1[7] + a2[7] + a3[7]) * inv;
    uint4 o;
    o.x = pack2(x0, x1); o.y = pack2(x2, x3); o.z = pack2(x4, x5); o.w = pack2(x6, x7);
    ((uint4*)(xo + (size_t)w * D))[hl] = o;
}

// gemm5 body: 32-row tile, 256 threads, A staged in LDS, B from L2, LN epilogue.
__device__ __forceinline__ void gemm_tile_body(
    const unsigned short* __restrict__ X, const unsigned short* __restrict__ Wt,
    const float* __restrict__ bias, const float* __restrict__ gamma,
    const float* __restrict__ beta, int N, float* __restrict__ Y, int row0, int t,
    __hip_bfloat16 (*As)[LDA], float (*red_s)[4], float (*red_q)[4]) {
    int lane = t & 63;
    int w = t >> 6;
    int l15 = lane & 15;
    int l4 = lane >> 4;

    {
        const uint4* Xg = (const uint4*)&X[(size_t)row0 * D];
        #pragma unroll
        for (int j = 0; j < 4; ++j) {
            int f = j * 256 + t;
            int lr = f >> 5;
            int c = f & 31;
            uint4 v = {0, 0, 0, 0};
            if (row0 + lr < N) v = Xg[(size_t)lr * 32 + c];
            *(uint4*)&As[lr][c * 8] = v;
        }
    }

    f32x4 acc[2][4];
    f32x4 zero = {0.f, 0.f, 0.f, 0.f};
    #pragma unroll
    for (int fr = 0; fr < 2; fr++)
        #pragma unroll
        for (int fc = 0; fc < 4; fc++)
            acc[fr][fc] = zero;

    __syncthreads();

    const uint4* Bg = (const uint4*)Wt;
    int colB = w * 64 + l15;
    #pragma unroll
    for (int ks8 = 0; ks8 < 8; ++ks8) {
        uint4 bq[4];
        #pragma unroll
        for (int fc = 0; fc < 4; ++fc)
            bq[fc] = Bg[(size_t)(colB + fc * 16) * 32 + ks8 * 4 + l4];
        bf16x8 af[2];
        #pragma unroll
        for (int fr = 0; fr < 2; ++fr)
            af[fr] = *(const bf16x8*)&As[fr * 16 + l15][ks8 * 32 + l4 * 8];
        #pragma unroll
        for (int fr = 0; fr < 2; ++fr)
            #pragma unroll
            for (int fc = 0; fc < 4; ++fc)
                acc[fr][fc] = __builtin_amdgcn_mfma_f32_16x16x32_bf16(
                    af[fr], *(bf16x8*)&bq[fc], acc[fr][fc], 0, 0, 0);
    }

    float bias_c[4], gam_c[4], bet_c[4];
    #pragma unroll
    for (int fc = 0; fc < 4; fc++) {
        int col = w * 64 + fc * 16 + l15;
        bias_c[fc] = bias[col];
        gam_c[fc]  = gamma[col];
        bet_c[fc]  = beta[col];
    }

    #pragma unroll
    for (int fr = 0; fr < 2; fr++) {
        #pragma unroll
        for (int r = 0; r < 4; r++) {
            int row = fr * 16 + l4 * 4 + r;
            float s = 0.f, q = 0.f;
            #pragma unroll
            for (int fc = 0; fc < 4; fc++) {
                float v = acc[fr][fc][r] + bias_c[fc];
                v = fmaxf(v, 0.f);
                acc[fr][fc][r] = v;
                s += v;
                q += v * v;
            }
            #pragma unroll
            for (int m = 1; m < 16; m <<= 1) {
                s += __shfl_xor(s, m);
                q += __shfl_xor(q, m);
            }
            if (l15 == 0) { red_s[row][w] = s; red_q[row][w] = q; }
        }
    }
    __syncthreads();

    #pragma unroll
    for (int fr = 0; fr < 2; fr++) {
        #pragma unroll
        for (int r = 0; r < 4; r++) {
            int row = fr * 16 + l4 * 4 + r;
            int grow = row0 + row;
            if (grow >= N) continue;
            float s = red_s[row][0] + red_s[row][1] + red_s[row][2] + red_s[row][3];
            float q = red_q[row][0] + red_q[row][1] + red_q[row][2] + red_q[row][3];
            float mu  = s * (1.0f / 256.0f);
            float var = q * (1.0f / 256.0f) - mu * mu;
            float rstd = rsqrtf(var + 1e-5f);
            #pragma unroll
            for (int fc = 0; fc < 4; fc++) {
                int col = w * 64 + fc * 16 + l15;
                Y[(size_t)grow * D + col] = (acc[fr][fc][r] - mu) * rstd * gam_c[fc] + bet_c[fc];
            }
        }
    }
}

// ======================= FAST PATH kernels =======================

__global__ void k_prep(const float* __restrict__ uf, const float* __restrict__ itf,
                       const float* __restrict__ Wu, const float* __restrict__ Wi,
                       unsigned short* __restrict__ feat_bf,
                       unsigned short* __restrict__ Wt_u, unsigned short* __restrict__ Wt_i,
                       const int* __restrict__ iu_e, int Eiu,
                       const int* __restrict__ ui_e, int Eui,
                       int* __restrict__ deg, int NU,
                       size_t nfU, size_t nfTot, int nbF) {
    int b = blockIdx.x;
    if (b < nbF) {
        size_t base = ((size_t)b * 256 + threadIdx.x) * 8;
        if (base < nfTot) {
            const float* s = (base < nfU) ? (uf + base) : (itf + (base - nfU));
            float4 f0 = *(const float4*)s;
            float4 f1 = *(const float4*)(s + 4);
            ushort4 o0, o1;
            o0.x = f2bf(f0.x); o0.y = f2bf(f0.y); o0.z = f2bf(f0.z); o0.w = f2bf(f0.w);
            o1.x = f2bf(f1.x); o1.y = f2bf(f1.y); o1.z = f2bf(f1.z); o1.w = f2bf(f1.w);
            ((ushort4*)(feat_bf + base))[0] = o0;
            ((ushort4*)(feat_bf + base))[1] = o1;
        }
    } else if (b < nbF + 512) {
        int b2 = b - nbF;
        const float* W = (b2 < 256) ? Wu : Wi;
        unsigned short* Wt = (b2 < 256) ? Wt_u : Wt_i;
        int k = b2 & 255;
        int c = threadIdx.x;
        Wt[(size_t)c * 256 + k] = f2bf(W[(size_t)k * 256 + c]);
    } else {
        int e = (b - nbF - 512) * 256 + threadIdx.x;
        if (e < Eiu) {
            atomicAdd(&deg[iu_e[Eiu + e]], 1);
        } else if (e < Eiu + Eui) {
            int e2 = e - Eiu;
            atomicAdd(&deg[NU + ui_e[Eui + e2]], 1);
        }
    }
}

__global__ void k_scan_block(const int* __restrict__ deg, int N,
                             int* __restrict__ rs, int* __restrict__ bsums) {
    __shared__ int s[1024];
    int base = blockIdx.x * 1024;
    int t = threadIdx.x;
    int v = (base + t < N) ? deg[base + t] : 0;
    s[t] = v;
    __syncthreads();
    for (int off = 1; off < 1024; off <<= 1) {
        int add = (t >= off) ? s[t - off] : 0;
        __syncthreads();
        s[t] += add;
        __syncthreads();
    }
    if (base + t < N) rs[base + t + 1] = s[t];
    if (t == 1023) bsums[blockIdx.x] = s[1023];
}

__global__ void k_scan_sums(int* __restrict__ bsums, int nb) {
    __shared__ int s[1024];
    int t = threadIdx.x;
    int v = (t < nb) ? bsums[t] : 0;
    s[t] = v;
    __syncthreads();
    for (int off = 1; off < 1024; off <<= 1) {
        int add = (t >= off) ? s[t - off] : 0;
        __syncthreads();
        s[t] += add;
        __syncthreads();
    }
    if (t < nb) bsums[t] = s[t] - v;
}

__global__ void k_finalize(int N, int* __restrict__ rs, int* __restrict__ cur,
                           const int* __restrict__ bsums) {
    int i = blockIdx.x * blockDim.x + threadIdx.x;
    if (i < N) {
        int v = rs[i + 1] + bsums[i >> 10];
        rs[i + 1] = v;
        cur[i + 1] = v;
    }
    if (i == 0) { rs[0] = 0; cur[0] = 0; }
}

__global__ void k_fill2(const int* __restrict__ iu_e, int Eiu,
                        const int* __restrict__ ui_e, int Eui,
                        int* __restrict__ cur, int NU,
                        int* __restrict__ csr) {
    int e = blockIdx.x * blockDim.x + threadIdx.x;
    if (e < Eiu) {
        int d = iu_e[Eiu + e];
        int p = atomicAdd(&cur[d], 1);
        csr[p] = iu_e[e];
    } else if (e < Eiu + Eui) {
        int e2 = e - Eiu;
        int d = ui_e[Eui + e2];
        int p = atomicAdd(&cur[NU + d], 1);
        csr[p] = ui_e[e2];
    }
}

// msg for USERS only
__global__ void k_msgU(const unsigned short* __restrict__ uf_bf,
                       const unsigned short* __restrict__ if_bf,
                       const int* __restrict__ rs, const int* __restrict__ csr,
                       unsigned short* __restrict__ x_u, int NU) {
    int pair = (blockIdx.x * blockDim.x + threadIdx.x) >> 6;
    msg_pair_body(if_bf, uf_bf, rs, csr, x_u, 0, NU, pair, threadIdx.x & 63);
}

// MIX: blocks [0,nbMsgI) run msg for ITEMS; blocks [nbMsgI,..) run gemm for USERS.
__launch_bounds__(256)
__global__ void k_mix(const unsigned short* __restrict__ uf_bf,
                      const unsigned short* __restrict__ if_bf,
                      const int* __restrict__ rs, const int* __restrict__ csr,
                      unsigned short* __restrict__ x_i,
                      const unsigned short* __restrict__ x_u,
                      const unsigned short* __restrict__ Wt_u,
                      const float* __restrict__ bu,
                      const float* __restrict__ gamma, const float* __restrict__ beta,
                      int NU, int NI, int nbMsgI, float* __restrict__ out) {
    __shared__ __align__(16) __hip_bfloat16 As[BM2][LDA];
    __shared__ float red_s[BM2][4];
    __shared__ float red_q[BM2][4];
    int t = threadIdx.x;
    if (blockIdx.x < nbMsgI) {
        int pair = (blockIdx.x * 256 + t) >> 6;
        msg_pair_body(uf_bf, if_bf, rs, csr, x_i, NU, NI, pair, t & 63);
    } else {
        int b = blockIdx.x - nbMsgI;
        gemm_tile_body(x_u, Wt_u, bu, gamma, beta, NU, out, b * BM2, t, As, red_s, red_q);
    }
}

// gemm for ITEMS only
__launch_bounds__(256)
__global__ void k_gemmI(const unsigned short* __restrict__ x_i,
                        const unsigned short* __restrict__ Wt_i,
                        const float* __restrict__ bi,
                        const float* __restrict__ gamma, const float* __restrict__ beta,
                        int NU, int NI, float* __restrict__ out) {
    __shared__ __align__(16) __hip_bfloat16 As[BM2][LDA];
    __shared__ float red_s[BM2][4];
    __shared__ float red_q[BM2][4];
    gemm_tile_body(x_i, Wt_i, bi, gamma, beta, NI, out + (size_t)NU * D,
                   blockIdx.x * BM2, threadIdx.x, As, red_s, red_q);
}

// ======================= FALLBACK PATH (R2, small-ws) =======================

__global__ void k_hist(const int* __restrict__ dst, int E, int* __restrict__ deg) {
    int e = blockIdx.x * blockDim.x + threadIdx.x;
    if (e < E) atomicAdd(&deg[dst[e]], 1);
}

__global__ void k_finalize_rs(int N, int* __restrict__ rs, const int* __restrict__ bsums) {
    int i = blockIdx.x * blockDim.x + threadIdx.x;
    if (i < N) rs[i + 1] += bsums[i >> 10];
    if (i == 0) rs[0] = 0;
}

__global__ void k_fill(const int* __restrict__ src, const int* __restrict__ dst, int E,
                       const int* __restrict__ rs, int* __restrict__ cursor,
                       int* __restrict__ csr) {
    int e = blockIdx.x * blockDim.x + threadIdx.x;
    if (e < E) {
        int d = dst[e];
        int p = atomicAdd(&cursor[d], 1);
        csr[rs[d] + p] = src[e];
    }
}

__global__ void k_msg_x(const float* __restrict__ srcf, const float* __restrict__ tgtf,
                        const int* __restrict__ rs, const int* __restrict__ csr,
                        int N, float* __restrict__ xout) {
    int wave = (blockIdx.x * blockDim.x + threadIdx.x) >> 6;
    int lane = threadIdx.x & 63;
    if (wave >= N) return;
    int s0 = rs[wave], s1 = rs[wave + 1];
    float4 acc = make_float4(0.f, 0.f, 0.f, 0.f);
    for (int i = s0; i < s1; i++) {
        int s = csr[i];
        float4 f = *(const float4*)&srcf[(size_t)s * D + lane * 4];
        acc.x += f.x; acc.y += f.y; acc.z += f.z; acc.w += f.w;
    }
    int cnt = s1 - s0;
    float inv = 1.0f / (float)(cnt > 0 ? cnt : 1);
    float4 t = *(const float4*)&tgtf[(size_t)wave * D + lane * 4];
    float4 x;
    x.x = t.x + acc.x * inv;
    x.y = t.y + acc.y * inv;
    x.z = t.z + acc.z * inv;
    x.w = t.w + acc.w * inv;
    *(float4*)&xout[(size_t)wave * D + lane * 4] = x;
}

__global__ void k_wcvt(const float* __restrict__ W0, const float* __restrict__ W1,
                       __hip_bfloat16* __restrict__ Wt0, __hip_bfloat16* __restrict__ Wt1) {
    int b = blockIdx.x;
    const float* W = (b < 256) ? W0 : W1;
    __hip_bfloat16* Wt = (b < 256) ? Wt0 : Wt1;
    int k = b & 255;
    int c = threadIdx.x;
    Wt[(size_t)c * 256 + k] = __float2bfloat16(W[(size_t)k * 256 + c]);
}

__launch_bounds__(256)
__global__ void k_gemm_mfma_ln(const float* __restrict__ X,
                               const __hip_bfloat16* __restrict__ Wt,
                               const float* __restrict__ bias,
                               const float* __restrict__ gamma,
                               const float* __restrict__ beta,
                               int N, float* __restrict__ Y) {
    __shared__ __hip_bfloat16 As[BM][LDK];
    __shared__ __hip_bfloat16 Bs[D][LDK];
    __shared__ float red_s[BM][4];
    __shared__ float red_q[BM][4];

    int t = threadIdx.x;
    int lane = t & 63;
    int w = t >> 6;
    int l15 = lane & 15;
    int l4 = lane >> 4;
    int row0 = blockIdx.x * BM;

    f32x4 acc[4][4];
    f32x4 zero = {0.f, 0.f, 0.f, 0.f};
    #pragma unroll
    for (int fr = 0; fr < 4; fr++)
        #pragma unroll
        for (int fc = 0; fc < 4; fc++)
            acc[fr][fc] = zero;

    for (int k0 = 0; k0 < D; k0 += 64) {
        {
            int i = t >> 2;
            int kq = (t & 3) * 16;
            int r = row0 + i;
            float4 f[4];
            if (r < N) {
                const float4* p = (const float4*)&X[(size_t)r * D + k0 + kq];
                f[0] = p[0]; f[1] = p[1]; f[2] = p[2]; f[3] = p[3];
            } else {
                float4 z4 = make_float4(0.f, 0.f, 0.f, 0.f);
                f[0] = z4; f[1] = z4; f[2] = z4; f[3] = z4;
            }
            __hip_bfloat16 vb[16];
            #pragma unroll
            for (int q = 0; q < 4; q++) {
                vb[q * 4 + 0] = __float2bfloat16(f[q].x);
                vb[q * 4 + 1] = __float2bfloat16(f[q].y);
                vb[q * 4 + 2] = __float2bfloat16(f[q].z);
                vb[q * 4 + 3] = __float2bfloat16(f[q].w);
            }
            *(uint4*)&As[i][kq]     = *(uint4*)&vb[0];
            *(uint4*)&As[i][kq + 8] = *(uint4*)&vb[8];
        }
        #pragma unroll
        for (int pass = 0; pass < 4; pass++) {
            int c = pass * 64 + (t >> 2);
            int kq = (t & 3) * 16;
            const uint4* p = (const uint4*)&Wt[(size_t)c * D + k0 + kq];
            uint4 b0 = p[0], b1 = p[1];
            *(uint4*)&Bs[c][kq]     = b0;
            *(uint4*)&Bs[c][kq + 8] = b1;
        }
        __syncthreads();

        #pragma unroll
        for (int ks = 0; ks < 2; ks++) {
            bf16x8 af[4], bg[4];
            #pragma unroll
            for (int fr = 0; fr < 4; fr++)
                af[fr] = *(const bf16x8*)&As[fr * 16 + l15][ks * 32 + l4 * 8];
            #pragma unroll
            for (int fc = 0; fc < 4; fc++)
                bg[fc] = *(const bf16x8*)&Bs[w * 64 + fc * 16 + l15][ks * 32 + l4 * 8];
            #pragma unroll
            for (int fr = 0; fr < 4; fr++)
                #pragma unroll
                for (int fc = 0; fc < 4; fc++)
                    acc[fr][fc] = __builtin_amdgcn_mfma_f32_16x16x32_bf16(
                        af[fr], bg[fc], acc[fr][fc], 0, 0, 0);
        }
        __syncthreads();
    }

    float bias_c[4], gam_c[4], bet_c[4];
    #pragma unroll
    for (int fc = 0; fc < 4; fc++) {
        int col = w * 64 + fc * 16 + l15;
        bias_c[fc] = bias[col];
        gam_c[fc]  = gamma[col];
        bet_c[fc]  = beta[col];
    }

    #pragma unroll
    for (int fr = 0; fr < 4; fr++) {
        #pragma unroll
        for (int r = 0; r < 4; r++) {
            int row = fr * 16 + l4 * 4 + r;
            float s = 0.f, q = 0.f;
            #pragma unroll
            for (int fc = 0; fc < 4; fc++) {
                float v = acc[fr][fc][r] + bias_c[fc];
                v = fmaxf(v, 0.f);
                acc[fr][fc][r] = v;
                s += v;
                q += v * v;
            }
            #pragma unroll
            for (int m = 1; m < 16; m <<= 1) {
                s += __shfl_xor(s, m);
                q += __shfl_xor(q, m);
            }
            if (l15 == 0) { red_s[row][w] = s; red_q[row][w] = q; }
        }
    }
    __syncthreads();

    #pragma unroll
    for (int fr = 0; fr < 4; fr++) {
        #pragma unroll
        for (int r = 0; r < 4; r++) {
            int row = fr * 16 + l4 * 4 + r;
            int grow = row0 + row;
            if (grow >= N) continue;
            float s = red_s[row][0] + red_s[row][1] + red_s[row][2] + red_s[row][3];
            float q = red_q[row][0] + red_q[row][1] + red_q[row][2] + red_q[row][3];
            float mu  = s * (1.0f / 256.0f);
            float var = q * (1.0f / 256.0f) - mu * mu;
            float rstd = rsqrtf(var + 1e-5f);
            #pragma unroll
            for (int fc = 0; fc < 4; fc++) {
                int col = w * 64 + fc * 16 + l15;
                Y[(size_t)grow * D + col] = (acc[fr][fc][r] - mu) * rstd * gam_c[fc] + bet_c[fc];
            }
        }
    }
}

// ======================= launch =======================

extern "C" void kernel_launch(void* const* d_in, const int* in_sizes, int n_in,
                              void* d_out, int out_size, void* d_ws, size_t ws_size,
                              hipStream_t stream) {
    const float* uf    = (const float*)d_in[0];
    const float* itf   = (const float*)d_in[1];
    const int*   ui_e  = (const int*)d_in[2];   // [2, Eui] user->item
    const int*   iu_e  = (const int*)d_in[3];   // [2, Eiu] item->user
    const float* Wu    = (const float*)d_in[4];
    const float* bu    = (const float*)d_in[5];
    const float* Wi    = (const float*)d_in[6];
    const float* bi    = (const float*)d_in[7];
    const float* gamma = (const float*)d_in[8];
    const float* beta  = (const float*)d_in[9];

    int NU  = in_sizes[0] / D;
    int NI  = in_sizes[1] / D;
    int Eui = in_sizes[2] / 2;
    int Eiu = in_sizes[3] / 2;
    int Nmax = NU > NI ? NU : NI;
    int Ntot = NU + NI;
    int Etot = Eiu + Eui;

    float* out   = (float*)d_out;
    size_t nfU = (size_t)NU * D;
    size_t nfI = (size_t)NI * D;
    size_t nfTot = nfU + nfI;

    // fast-path ws layout
    unsigned short* uf_bf = (unsigned short*)d_ws;     // nfU
    unsigned short* if_bf = uf_bf + nfU;               // nfI
    unsigned short* x_u   = if_bf + nfI;               // nfU
    unsigned short* x_i   = x_u + nfU;                 // nfI
    unsigned short* Wt_u2 = x_i + nfI;                 // 65536
    unsigned short* Wt_i2 = Wt_u2 + 65536;             // 65536
    int* deg2  = (int*)(Wt_i2 + 65536);                // Ntot
    int* rs2   = deg2 + Ntot;                          // Ntot+1
    int* cur2  = rs2 + Ntot + 1;                       // Ntot+1
    int* bsums = cur2 + Ntot + 1;                      // 1024
    int* csr2  = bsums + 1024;                         // Etot
    size_t needed = (size_t)((char*)(csr2 + Etot) - (char*)d_ws);

    if (ws_size >= needed) {
        int nbF = (int)((nfTot + 2047) / 2048);
        int nbH = (Etot + 255) / 256;
        hipMemsetAsync(deg2, 0, (size_t)Ntot * sizeof(int), stream);
        k_prep<<<nbF + 512 + nbH, 256, 0, stream>>>(uf, itf, Wu, Wi, uf_bf, Wt_u2, Wt_i2,
                                                    iu_e, Eiu, ui_e, Eui, deg2, NU,
                                                    nfU, nfTot, nbF);
        int nb = (Ntot + 1023) / 1024;
        k_scan_block<<<nb, 1024, 0, stream>>>(deg2, Ntot, rs2, bsums);
        k_scan_sums<<<1, 1024, 0, stream>>>(bsums, nb);
        k_finalize<<<(Ntot + 255) / 256, 256, 0, stream>>>(Ntot, rs2, cur2, bsums);
        k_fill2<<<nbH, 256, 0, stream>>>(iu_e, Eiu, ui_e, Eui, cur2, NU, csr2);

        // stage 1: msg for users
        int pairsU = (NU + 1) / 2;
        k_msgU<<<(pairsU + 3) / 4, 256, 0, stream>>>(uf_bf, if_bf, rs2, csr2, x_u, NU);
        // stage 2: msg for items MIXED with gemm for users
        int pairsI = (NI + 1) / 2;
        int nbMsgI = (pairsI + 3) / 4;
        int nbGemmU = (NU + BM2 - 1) / BM2;
        k_mix<<<nbMsgI + nbGemmU, 256, 0, stream>>>(uf_bf, if_bf, rs2, csr2, x_i, x_u,
                                                    Wt_u2, bu, gamma, beta,
                                                    NU, NI, nbMsgI, out);
        // stage 3: gemm for items
        int nbGemmI = (NI + BM2 - 1) / BM2;
        k_gemmI<<<nbGemmI, 256, 0, stream>>>(x_i, Wt_i2, bi, gamma, beta, NU, NI, out);
        return;
    }

    // ---------- fallback: R2 path (needs ~2.2 MB ws) ----------
    float* u_out = out;
    float* i_out = out + nfU;
    __hip_bfloat16* Wt_u = (__hip_bfloat16*)d_ws;
    __hip_bfloat16* Wt_i = Wt_u + 256 * 256;
    int* deg    = (int*)(Wt_i + 256 * 256);
    int* rs     = deg + Nmax;
    int* bs     = rs + Nmax + 1;
    int* cursor = bs + 1024;
    int* csr    = cursor + Nmax;

    k_wcvt<<<512, 256, 0, stream>>>(Wu, Wi, Wt_u, Wt_i);

    auto run_side = [&](const float* srcf, const float* tgtf, const int* edges, int E,
                        int N, const __hip_bfloat16* Wt, const float* bias, float* y) {
        const int* esrc = edges;
        const int* edst = edges + E;
        hipMemsetAsync(deg, 0, (size_t)N * sizeof(int), stream);
        hipMemsetAsync(cursor, 0, (size_t)N * sizeof(int), stream);
        k_hist<<<(E + 255) / 256, 256, 0, stream>>>(edst, E, deg);
        int nb = (N + 1023) / 1024;
        k_scan_block<<<nb, 1024, 0, stream>>>(deg, N, rs, bs);
        k_scan_sums<<<1, 1024, 0, stream>>>(bs, nb);
        k_finalize_rs<<<(N + 255) / 256, 256, 0, stream>>>(N, rs, bs);
        k_fill<<<(E + 255) / 256, 256, 0, stream>>>(esrc, edst, E, rs, cursor, csr);
        k_msg_x<<<(N + 3) / 4, 256, 0, stream>>>(srcf, tgtf, rs, csr, N, y);
        k_gemm_mfma_ln<<<(N + BM - 1) / BM, 256, 0, stream>>>(y, Wt, bias, gamma, beta, N, y);
    };

    run_side(itf, uf, iu_e, Eiu, NU, Wt_u, bu, u_out);
    run_side(uf, itf, ui_e, Eui, NI, Wt_i, bi, i_out);
}

// Round 13
// 225.189 us; speedup vs baseline: 1.1586x; 1.0592x over previous
//
#include <hip/hip_runtime.h>
#include <hip/hip_bf16.h>

#define D 256
#define BM 64
#define BM2 32    // gemm tile rows
#define LDA 264   // A-tile LDS k-stride (bf16 elems)
#define LDB 258   // Bs LDS k-stride (bf16 elems) — avoids 16-way bank conflict
#define LDK 72    // fallback-path pad

typedef __attribute__((ext_vector_type(8))) __bf16 bf16x8;
typedef __attribute__((ext_vector_type(4))) float f32x4;

__device__ __forceinline__ float bf2f(unsigned short u) {
    union { unsigned int i; float f; } c; c.i = ((unsigned int)u) << 16; return c.f;
}
__device__ __forceinline__ float bf2f_lo(unsigned int u) {
    union { unsigned int i; float f; } c; c.i = u << 16; return c.f;
}
__device__ __forceinline__ float bf2f_hi(unsigned int u) {
    union { unsigned int i; float f; } c; c.i = u & 0xffff0000u; return c.f;
}
__device__ __forceinline__ unsigned short f2bf(float f) {
    __hip_bfloat16 h = __float2bfloat16(f);
    return *reinterpret_cast<unsigned short*>(&h);
}
__device__ __forceinline__ unsigned int pack2(float lo, float hi) {
    return (unsigned int)f2bf(lo) | ((unsigned int)f2bf(hi) << 16);
}

// ======================= FAST PATH =======================

// blocks [0,nbF): feat fp32->bf16 ; [nbF,nbF+512): W->Wt[c][k] ; rest: edge histogram.
__global__ void k_prep(const float* __restrict__ uf, const float* __restrict__ itf,
                       const float* __restrict__ Wu, const float* __restrict__ Wi,
                       unsigned short* __restrict__ feat_bf,
                       unsigned short* __restrict__ Wt_u, unsigned short* __restrict__ Wt_i,
                       const int* __restrict__ iu_e, int Eiu,
                       const int* __restrict__ ui_e, int Eui,
                       int* __restrict__ deg, int NU,
                       size_t nfU, size_t nfTot, int nbF) {
    int b = blockIdx.x;
    if (b < nbF) {
        size_t base = ((size_t)b * 256 + threadIdx.x) * 8;
        if (base < nfTot) {
            const float* s = (base < nfU) ? (uf + base) : (itf + (base - nfU));
            float4 f0 = *(const float4*)s;
            float4 f1 = *(const float4*)(s + 4);
            ushort4 o0, o1;
            o0.x = f2bf(f0.x); o0.y = f2bf(f0.y); o0.z = f2bf(f0.z); o0.w = f2bf(f0.w);
            o1.x = f2bf(f1.x); o1.y = f2bf(f1.y); o1.z = f2bf(f1.z); o1.w = f2bf(f1.w);
            ((ushort4*)(feat_bf + base))[0] = o0;
            ((ushort4*)(feat_bf + base))[1] = o1;
        }
    } else if (b < nbF + 512) {
        int b2 = b - nbF;
        const float* W = (b2 < 256) ? Wu : Wi;
        unsigned short* Wt = (b2 < 256) ? Wt_u : Wt_i;
        int k = b2 & 255;
        int c = threadIdx.x;
        Wt[(size_t)c * 256 + k] = f2bf(W[(size_t)k * 256 + c]);
    } else {
        int e = (b - nbF - 512) * 256 + threadIdx.x;
        if (e < Eiu) {
            atomicAdd(&deg[iu_e[Eiu + e]], 1);
        } else if (e < Eiu + Eui) {
            int e2 = e - Eiu;
            atomicAdd(&deg[NU + ui_e[Eui + e2]], 1);
        }
    }
}

__global__ void k_scan_block(const int* __restrict__ deg, int N,
                             int* __restrict__ rs, int* __restrict__ bsums) {
    __shared__ int s[1024];
    int base = blockIdx.x * 1024;
    int t = threadIdx.x;
    int v = (base + t < N) ? deg[base + t] : 0;
    s[t] = v;
    __syncthreads();
    for (int off = 1; off < 1024; off <<= 1) {
        int add = (t >= off) ? s[t - off] : 0;
        __syncthreads();
        s[t] += add;
        __syncthreads();
    }
    if (base + t < N) rs[base + t + 1] = s[t];
    if (t == 1023) bsums[blockIdx.x] = s[1023];
}

__global__ void k_scan_sums(int* __restrict__ bsums, int nb) {
    __shared__ int s[1024];
    int t = threadIdx.x;
    int v = (t < nb) ? bsums[t] : 0;
    s[t] = v;
    __syncthreads();
    for (int off = 1; off < 1024; off <<= 1) {
        int add = (t >= off) ? s[t - off] : 0;
        __syncthreads();
        s[t] += add;
        __syncthreads();
    }
    if (t < nb) bsums[t] = s[t] - v;
}

__global__ void k_finalize(int N, int* __restrict__ rs, int* __restrict__ cur,
                           const int* __restrict__ bsums) {
    int i = blockIdx.x * blockDim.x + threadIdx.x;
    if (i < N) {
        int v = rs[i + 1] + bsums[i >> 10];
        rs[i + 1] = v;
        cur[i + 1] = v;
    }
    if (i == 0) { rs[0] = 0; cur[0] = 0; }
}

__global__ void k_fill2(const int* __restrict__ iu_e, int Eiu,
                        const int* __restrict__ ui_e, int Eui,
                        int* __restrict__ cur, int NU,
                        int* __restrict__ csr) {
    int e = blockIdx.x * blockDim.x + threadIdx.x;
    if (e < Eiu) {
        int d = iu_e[Eiu + e];
        int p = atomicAdd(&cur[d], 1);
        csr[p] = iu_e[e];
    } else if (e < Eiu + Eui) {
        int e2 = e - Eiu;
        int d = ui_e[Eui + e2];
        int p = atomicAdd(&cur[NU + d], 1);
        csr[p] = ui_e[e2];
    }
}

// x = bf16( tgt + mean(src rows) ); TWO rows per wave (half-wave each),
// 4-unrolled gather -> up to 8 independent row loads in flight. High-occupancy.
__global__ void k_msg2(const unsigned short* __restrict__ uf_bf,
                       const unsigned short* __restrict__ if_bf,
                       const int* __restrict__ rs, const int* __restrict__ csr,
                       unsigned short* __restrict__ x_u, unsigned short* __restrict__ x_i,
                       int NU, int NI) {
    int pair = (blockIdx.x * blockDim.x + threadIdx.x) >> 6;
    int lane = threadIdx.x & 63;
    int half = lane >> 5;
    int hl   = lane & 31;
    int Ntot = NU + NI;
    int wv = pair * 2 + half;
    if (wv >= Ntot) return;

    const unsigned short* src; const unsigned short* tgt; unsigned short* xo; int w;
    if (wv < NU) { src = if_bf; tgt = uf_bf; xo = x_u; w = wv; }
    else         { src = uf_bf; tgt = if_bf; xo = x_i; w = wv - NU; }

    int s0 = rs[wv], s1 = rs[wv + 1];
    float a0[8] = {}, a1[8] = {}, a2[8] = {}, a3[8] = {};

    int i = s0;
    for (; i + 4 <= s1; i += 4) {
        int e0 = csr[i], e1 = csr[i + 1], e2 = csr[i + 2], e3 = csr[i + 3];
        uint4 r0 = ((const uint4*)(src + (size_t)e0 * D))[hl];
        uint4 r1 = ((const uint4*)(src + (size_t)e1 * D))[hl];
        uint4 r2 = ((const uint4*)(src + (size_t)e2 * D))[hl];
        uint4 r3 = ((const uint4*)(src + (size_t)e3 * D))[hl];
        a0[0] += bf2f_lo(r0.x); a0[1] += bf2f_hi(r0.x); a0[2] += bf2f_lo(r0.y); a0[3] += bf2f_hi(r0.y);
        a0[4] += bf2f_lo(r0.z); a0[5] += bf2f_hi(r0.z); a0[6] += bf2f_lo(r0.w); a0[7] += bf2f_hi(r0.w);
        a1[0] += bf2f_lo(r1.x); a1[1] += bf2f_hi(r1.x); a1[2] += bf2f_lo(r1.y); a1[3] += bf2f_hi(r1.y);
        a1[4] += bf2f_lo(r1.z); a1[5] += bf2f_hi(r1.z); a1[6] += bf2f_lo(r1.w); a1[7] += bf2f_hi(r1.w);
        a2[0] += bf2f_lo(r2.x); a2[1] += bf2f_hi(r2.x); a2[2] += bf2f_lo(r2.y); a2[3] += bf2f_hi(r2.y);
        a2[4] += bf2f_lo(r2.z); a2[5] += bf2f_hi(r2.z); a2[6] += bf2f_lo(r2.w); a2[7] += bf2f_hi(r2.w);
        a3[0] += bf2f_lo(r3.x); a3[1] += bf2f_hi(r3.x); a3[2] += bf2f_lo(r3.y); a3[3] += bf2f_hi(r3.y);
        a3[4] += bf2f_lo(r3.z); a3[5] += bf2f_hi(r3.z); a3[6] += bf2f_lo(r3.w); a3[7] += bf2f_hi(r3.w);
    }
    for (; i < s1; ++i) {
        int e0 = csr[i];
        uint4 r0 = ((const uint4*)(src + (size_t)e0 * D))[hl];
        a0[0] += bf2f_lo(r0.x); a0[1] += bf2f_hi(r0.x); a0[2] += bf2f_lo(r0.y); a0[3] += bf2f_hi(r0.y);
        a0[4] += bf2f_lo(r0.z); a0[5] += bf2f_hi(r0.z); a0[6] += bf2f_lo(r0.w); a0[7] += bf2f_hi(r0.w);
    }

    int cnt = s1 - s0;
    float inv = 1.0f / (float)(cnt > 0 ? cnt : 1);
    uint4 tv = ((const uint4*)(tgt + (size_t)w * D))[hl];
    float x0 = bf2f_lo(tv.x) + (a0[0] + a1[0] + a2[0] + a3[0]) * inv;
    float x1 = bf2f_hi(tv.x) + (a0[1] + a1[1] + a2[1] + a3[1]) * inv;
    float x2 = bf2f_lo(tv.y) + (a0[2] + a1[2] + a2[2] + a3[2]) * inv;
    float x3 = bf2f_hi(tv.y) + (a0[3] + a1[3] + a2[3] + a3[3]) * inv;
    float x4 = bf2f_lo(tv.z) + (a0[4] + a1[4] + a2[4] + a3[4]) * inv;
    float x5 = bf2f_hi(tv.z) + (a0[5] + a1[5] + a2[5] + a3[5]) * inv;
    float x6 = bf2f_lo(tv.w) + (a0[6] + a1[6] + a2[6] + a3[6]) * inv;
    float x7 = bf2f_hi(tv.w) + (a0[7] + a1[7] + a2[7] + a3[7]) * inv;
    uint4 o;
    o.x = pack2(x0, x1); o.y = pack2(x2, x3); o.z = pack2(x4, x5); o.w = pack2(x6, x7);
    ((uint4*)(xo + (size_t)w * D))[hl] = o;
}

// ---- PERSISTENT GEMM: W fully resident in LDS; MFMA loop never touches global.
// 512 blocks x 512 threads (8 waves). Block b: side = (b>=256); stages its side's
// entire Wt (256x256 bf16 = 128 KB) into LDS once, then grid-strides over 32-row
// tiles: reg-prefetch next A -> LDS A-tile -> 32 pure-LDS MFMAs/wave -> LN -> store.
__launch_bounds__(512)
__global__ void k_gemm7(const unsigned short* __restrict__ x_u,
                        const unsigned short* __restrict__ x_i,
                        const unsigned short* __restrict__ Wt_u,
                        const unsigned short* __restrict__ Wt_i,
                        const float* __restrict__ bu, const float* __restrict__ bi,
                        const float* __restrict__ gamma, const float* __restrict__ beta,
                        int NU, int NI, float* __restrict__ out) {
    __shared__ __align__(16) __hip_bfloat16 Bs[256][LDB];  // 132096 B
    __shared__ __align__(16) __hip_bfloat16 As[BM2][LDA];  // 16896 B
    __shared__ float red_s[BM2][8];                         // 1024 B
    __shared__ float red_q[BM2][8];                         // 1024 B

    int b = blockIdx.x;
    bool isU = b < 256;
    const unsigned short* X  = isU ? x_u : x_i;
    const unsigned short* Wt = isU ? Wt_u : Wt_i;
    const float* bias        = isU ? bu : bi;
    float* Y                 = isU ? out : out + (size_t)NU * D;
    int N                    = isU ? NU : NI;
    int idx0 = b & 255;
    int ntiles = (N + BM2 - 1) / BM2;

    int t = threadIdx.x;     // 0..511
    int lane = t & 63;
    int w = t >> 6;          // 0..7
    int l15 = lane & 15;
    int l4 = lane >> 4;

    // ---- stage entire W into LDS (once): 8192 uint4, 16 per thread, coalesced
    {
        const uint4* Wg = (const uint4*)Wt;
        #pragma unroll
        for (int j = 0; j < 16; ++j) {
            int f = j * 512 + t;
            int col = f >> 5;
            int c = f & 31;
            uint4 v = Wg[(size_t)col * 32 + c];
            *(uint4*)&Bs[col][c * 8] = v;
        }
    }

    // per-wave constants: cols [w*32, w*32+32)
    float bias_c[2], gam_c[2], bet_c[2];
    #pragma unroll
    for (int fc = 0; fc < 2; ++fc) {
        int col = w * 32 + fc * 16 + l15;
        bias_c[fc] = bias[col];
        gam_c[fc]  = gamma[col];
        bet_c[fc]  = beta[col];
    }

    int f0 = t, f1 = 512 + t;
    int lr0 = f0 >> 5, c0 = f0 & 31;
    int lr1 = f1 >> 5, c1 = f1 & 31;

    // prefetch first A tile into regs
    int tile = idx0;
    uint4 aR0 = {0, 0, 0, 0}, aR1 = {0, 0, 0, 0};
    if (tile < ntiles) {
        const uint4* Xg = (const uint4*)&X[(size_t)tile * BM2 * D];
        if (tile * BM2 + lr0 < N) aR0 = Xg[(size_t)lr0 * 32 + c0];
        if (tile * BM2 + lr1 < N) aR1 = Xg[(size_t)lr1 * 32 + c1];
    }
    __syncthreads();   // Bs ready

    for (; tile < ntiles; tile += 256) {
        int row0 = tile * BM2;
        // write prefetched A to LDS
        *(uint4*)&As[lr0][c0 * 8] = aR0;
        *(uint4*)&As[lr1][c1 * 8] = aR1;
        __syncthreads();   // As ready

        // prefetch next tile (overlaps MFMA + epilogue below)
        int nt = tile + 256;
        if (nt < ntiles) {
            const uint4* Xg = (const uint4*)&X[(size_t)nt * BM2 * D];
            uint4 z = {0, 0, 0, 0};
            aR0 = z; aR1 = z;
            if (nt * BM2 + lr0 < N) aR0 = Xg[(size_t)lr0 * 32 + c0];
            if (nt * BM2 + lr1 < N) aR1 = Xg[(size_t)lr1 * 32 + c1];
        }

        // ---- MFMA: pure LDS
        f32x4 acc[2][2];
        f32x4 zero = {0.f, 0.f, 0.f, 0.f};
        acc[0][0] = zero; acc[0][1] = zero; acc[1][0] = zero; acc[1][1] = zero;
        #pragma unroll
        for (int ks8 = 0; ks8 < 8; ++ks8) {
            bf16x8 af[2], bg[2];
            #pragma unroll
            for (int fr = 0; fr < 2; ++fr)
                af[fr] = *(const bf16x8*)&As[fr * 16 + l15][ks8 * 32 + l4 * 8];
            #pragma unroll
            for (int fc = 0; fc < 2; ++fc)
                bg[fc] = *(const bf16x8*)&Bs[w * 32 + fc * 16 + l15][ks8 * 32 + l4 * 8];
            #pragma unroll
            for (int fr = 0; fr < 2; ++fr)
                #pragma unroll
                for (int fc = 0; fc < 2; ++fc)
                    acc[fr][fc] = __builtin_amdgcn_mfma_f32_16x16x32_bf16(
                        af[fr], bg[fc], acc[fr][fc], 0, 0, 0);
        }

        // ---- epilogue: bias + relu + per-row partial sums (this wave's 32 cols)
        #pragma unroll
        for (int fr = 0; fr < 2; ++fr) {
            #pragma unroll
            for (int r = 0; r < 4; ++r) {
                int row = fr * 16 + l4 * 4 + r;
                float s = 0.f, q = 0.f;
                #pragma unroll
                for (int fc = 0; fc < 2; ++fc) {
                    float v = acc[fr][fc][r] + bias_c[fc];
                    v = fmaxf(v, 0.f);
                    acc[fr][fc][r] = v;
                    s += v;
                    q += v * v;
                }
                #pragma unroll
                for (int m = 1; m < 16; m <<= 1) {
                    s += __shfl_xor(s, m);
                    q += __shfl_xor(q, m);
                }
                if (l15 == 0) { red_s[row][w] = s; red_q[row][w] = q; }
            }
        }
        __syncthreads();   // red ready

        #pragma unroll
        for (int fr = 0; fr < 2; ++fr) {
            #pragma unroll
            for (int r = 0; r < 4; ++r) {
                int row = fr * 16 + l4 * 4 + r;
                int grow = row0 + row;
                if (grow >= N) continue;
                float s = red_s[row][0] + red_s[row][1] + red_s[row][2] + red_s[row][3]
                        + red_s[row][4] + red_s[row][5] + red_s[row][6] + red_s[row][7];
                float q = red_q[row][0] + red_q[row][1] + red_q[row][2] + red_q[row][3]
                        + red_q[row][4] + red_q[row][5] + red_q[row][6] + red_q[row][7];
                float mu  = s * (1.0f / 256.0f);
                float var = q * (1.0f / 256.0f) - mu * mu;
                float rstd = rsqrtf(var + 1e-5f);
                #pragma unroll
                for (int fc = 0; fc < 2; ++fc) {
                    int col = w * 32 + fc * 16 + l15;
                    Y[(size_t)grow * D + col] = (acc[fr][fc][r] - mu) * rstd * gam_c[fc] + bet_c[fc];
                }
            }
        }
        __syncthreads();   // protect As/red_s overwrite next iteration
    }
}

// ======================= FALLBACK PATH (R2, small-ws) =======================

__global__ void k_hist(const int* __restrict__ dst, int E, int* __restrict__ deg) {
    int e = blockIdx.x * blockDim.x + threadIdx.x;
    if (e < E) atomicAdd(&deg[dst[e]], 1);
}

__global__ void k_finalize_rs(int N, int* __restrict__ rs, const int* __restrict__ bsums) {
    int i = blockIdx.x * blockDim.x + threadIdx.x;
    if (i < N) rs[i + 1] += bsums[i >> 10];
    if (i == 0) rs[0] = 0;
}

__global__ void k_fill(const int* __restrict__ src, const int* __restrict__ dst, int E,
                       const int* __restrict__ rs, int* __restrict__ cursor,
                       int* __restrict__ csr) {
    int e = blockIdx.x * blockDim.x + threadIdx.x;
    if (e < E) {
        int d = dst[e];
        int p = atomicAdd(&cursor[d], 1);
        csr[rs[d] + p] = src[e];
    }
}

__global__ void k_msg_x(const float* __restrict__ srcf, const float* __restrict__ tgtf,
                        const int* __restrict__ rs, const int* __restrict__ csr,
                        int N, float* __restrict__ xout) {
    int wave = (blockIdx.x * blockDim.x + threadIdx.x) >> 6;
    int lane = threadIdx.x & 63;
    if (wave >= N) return;
    int s0 = rs[wave], s1 = rs[wave + 1];
    float4 acc = make_float4(0.f, 0.f, 0.f, 0.f);
    for (int i = s0; i < s1; i++) {
        int s = csr[i];
        float4 f = *(const float4*)&srcf[(size_t)s * D + lane * 4];
        acc.x += f.x; acc.y += f.y; acc.z += f.z; acc.w += f.w;
    }
    int cnt = s1 - s0;
    float inv = 1.0f / (float)(cnt > 0 ? cnt : 1);
    float4 t = *(const float4*)&tgtf[(size_t)wave * D + lane * 4];
    float4 x;
    x.x = t.x + acc.x * inv;
    x.y = t.y + acc.y * inv;
    x.z = t.z + acc.z * inv;
    x.w = t.w + acc.w * inv;
    *(float4*)&xout[(size_t)wave * D + lane * 4] = x;
}

__global__ void k_wcvt(const float* __restrict__ W0, const float* __restrict__ W1,
                       __hip_bfloat16* __restrict__ Wt0, __hip_bfloat16* __restrict__ Wt1) {
    int b = blockIdx.x;
    const float* W = (b < 256) ? W0 : W1;
    __hip_bfloat16* Wt = (b < 256) ? Wt0 : Wt1;
    int k = b & 255;
    int c = threadIdx.x;
    Wt[(size_t)c * 256 + k] = __float2bfloat16(W[(size_t)k * 256 + c]);
}

__launch_bounds__(256)
__global__ void k_gemm_mfma_ln(const float* __restrict__ X,
                               const __hip_bfloat16* __restrict__ Wt,
                               const float* __restrict__ bias,
                               const float* __restrict__ gamma,
                               const float* __restrict__ beta,
                               int N, float* __restrict__ Y) {
    __shared__ __hip_bfloat16 As[BM][LDK];
    __shared__ __hip_bfloat16 Bs[D][LDK];
    __shared__ float red_s[BM][4];
    __shared__ float red_q[BM][4];

    int t = threadIdx.x;
    int lane = t & 63;
    int w = t >> 6;
    int l15 = lane & 15;
    int l4 = lane >> 4;
    int row0 = blockIdx.x * BM;

    f32x4 acc[4][4];
    f32x4 zero = {0.f, 0.f, 0.f, 0.f};
    #pragma unroll
    for (int fr = 0; fr < 4; fr++)
        #pragma unroll
        for (int fc = 0; fc < 4; fc++)
            acc[fr][fc] = zero;

    for (int k0 = 0; k0 < D; k0 += 64) {
        {
            int i = t >> 2;
            int kq = (t & 3) * 16;
            int r = row0 + i;
            float4 f[4];
            if (r < N) {
                const float4* p = (const float4*)&X[(size_t)r * D + k0 + kq];
                f[0] = p[0]; f[1] = p[1]; f[2] = p[2]; f[3] = p[3];
            } else {
                float4 z4 = make_float4(0.f, 0.f, 0.f, 0.f);
                f[0] = z4; f[1] = z4; f[2] = z4; f[3] = z4;
            }
            __hip_bfloat16 vb[16];
            #pragma unroll
            for (int q = 0; q < 4; q++) {
                vb[q * 4 + 0] = __float2bfloat16(f[q].x);
                vb[q * 4 + 1] = __float2bfloat16(f[q].y);
                vb[q * 4 + 2] = __float2bfloat16(f[q].z);
                vb[q * 4 + 3] = __float2bfloat16(f[q].w);
            }
            *(uint4*)&As[i][kq]     = *(uint4*)&vb[0];
            *(uint4*)&As[i][kq + 8] = *(uint4*)&vb[8];
        }
        #pragma unroll
        for (int pass = 0; pass < 4; pass++) {
            int c = pass * 64 + (t >> 2);
            int kq = (t & 3) * 16;
            const uint4* p = (const uint4*)&Wt[(size_t)c * D + k0 + kq];
            uint4 b0 = p[0], b1 = p[1];
            *(uint4*)&Bs[c][kq]     = b0;
            *(uint4*)&Bs[c][kq + 8] = b1;
        }
        __syncthreads();

        #pragma unroll
        for (int ks = 0; ks < 2; ks++) {
            bf16x8 af[4], bg[4];
            #pragma unroll
            for (int fr = 0; fr < 4; fr++)
                af[fr] = *(const bf16x8*)&As[fr * 16 + l15][ks * 32 + l4 * 8];
            #pragma unroll
            for (int fc = 0; fc < 4; fc++)
                bg[fc] = *(const bf16x8*)&Bs[w * 64 + fc * 16 + l15][ks * 32 + l4 * 8];
            #pragma unroll
            for (int fr = 0; fr < 4; fr++)
                #pragma unroll
                for (int fc = 0; fc < 4; fc++)
                    acc[fr][fc] = __builtin_amdgcn_mfma_f32_16x16x32_bf16(
                        af[fr], bg[fc], acc[fr][fc], 0, 0, 0);
        }
        __syncthreads();
    }

    float bias_c[4], gam_c[4], bet_c[4];
    #pragma unroll
    for (int fc = 0; fc < 4; fc++) {
        int col = w * 64 + fc * 16 + l15;
        bias_c[fc] = bias[col];
        gam_c[fc]  = gamma[col];
        bet_c[fc]  = beta[col];
    }

    #pragma unroll
    for (int fr = 0; fr < 4; fr++) {
        #pragma unroll
        for (int r = 0; r < 4; r++) {
            int row = fr * 16 + l4 * 4 + r;
            float s = 0.f, q = 0.f;
            #pragma unroll
            for (int fc = 0; fc < 4; fc++) {
                float v = acc[fr][fc][r] + bias_c[fc];
                v = fmaxf(v, 0.f);
                acc[fr][fc][r] = v;
                s += v;
                q += v * v;
            }
            #pragma unroll
            for (int m = 1; m < 16; m <<= 1) {
                s += __shfl_xor(s, m);
                q += __shfl_xor(q, m);
            }
            if (l15 == 0) { red_s[row][w] = s; red_q[row][w] = q; }
        }
    }
    __syncthreads();

    #pragma unroll
    for (int fr = 0; fr < 4; fr++) {
        #pragma unroll
        for (int r = 0; r < 4; r++) {
            int row = fr * 16 + l4 * 4 + r;
            int grow = row0 + row;
            if (grow >= N) continue;
            float s = red_s[row][0] + red_s[row][1] + red_s[row][2] + red_s[row][3];
            float q = red_q[row][0] + red_q[row][1] + red_q[row][2] + red_q[row][3];
            float mu  = s * (1.0f / 256.0f);
            float var = q * (1.0f / 256.0f) - mu * mu;
            float rstd = rsqrtf(var + 1e-5f);
            #pragma unroll
            for (int fc = 0; fc < 4; fc++) {
                int col = w * 64 + fc * 16 + l15;
                Y[(size_t)grow * D + col] = (acc[fr][fc][r] - mu) * rstd * gam_c[fc] + bet_c[fc];
            }
        }
    }
}

// ======================= launch =======================

extern "C" void kernel_launch(void* const* d_in, const int* in_sizes, int n_in,
                              void* d_out, int out_size, void* d_ws, size_t ws_size,
                              hipStream_t stream) {
    const float* uf    = (const float*)d_in[0];
    const float* itf   = (const float*)d_in[1];
    const int*   ui_e  = (const int*)d_in[2];   // [2, Eui] user->item
    const int*   iu_e  = (const int*)d_in[3];   // [2, Eiu] item->user
    const float* Wu    = (const float*)d_in[4];
    const float* bu    = (const float*)d_in[5];
    const float* Wi    = (const float*)d_in[6];
    const float* bi    = (const float*)d_in[7];
    const float* gamma = (const float*)d_in[8];
    const float* beta  = (const float*)d_in[9];

    int NU  = in_sizes[0] / D;
    int NI  = in_sizes[1] / D;
    int Eui = in_sizes[2] / 2;
    int Eiu = in_sizes[3] / 2;
    int Nmax = NU > NI ? NU : NI;
    int Ntot = NU + NI;
    int Etot = Eiu + Eui;

    float* out   = (float*)d_out;
    size_t nfU = (size_t)NU * D;
    size_t nfI = (size_t)NI * D;
    size_t nfTot = nfU + nfI;

    // fast-path ws layout
    unsigned short* uf_bf = (unsigned short*)d_ws;     // nfU
    unsigned short* if_bf = uf_bf + nfU;               // nfI
    unsigned short* x_u   = if_bf + nfI;               // nfU
    unsigned short* x_i   = x_u + nfU;                 // nfI
    unsigned short* Wt_u2 = x_i + nfI;                 // 65536
    unsigned short* Wt_i2 = Wt_u2 + 65536;             // 65536
    int* deg2  = (int*)(Wt_i2 + 65536);                // Ntot
    int* rs2   = deg2 + Ntot;                          // Ntot+1
    int* cur2  = rs2 + Ntot + 1;                       // Ntot+1
    int* bsums = cur2 + Ntot + 1;                      // 1024
    int* csr2  = bsums + 1024;                         // Etot
    size_t needed = (size_t)((char*)(csr2 + Etot) - (char*)d_ws);

    if (ws_size >= needed) {
        int nbF = (int)((nfTot + 2047) / 2048);
        int nbH = (Etot + 255) / 256;
        hipMemsetAsync(deg2, 0, (size_t)Ntot * sizeof(int), stream);
        k_prep<<<nbF + 512 + nbH, 256, 0, stream>>>(uf, itf, Wu, Wi, uf_bf, Wt_u2, Wt_i2,
                                                    iu_e, Eiu, ui_e, Eui, deg2, NU,
                                                    nfU, nfTot, nbF);
        int nb = (Ntot + 1023) / 1024;
        k_scan_block<<<nb, 1024, 0, stream>>>(deg2, Ntot, rs2, bsums);
        k_scan_sums<<<1, 1024, 0, stream>>>(bsums, nb);
        k_finalize<<<(Ntot + 255) / 256, 256, 0, stream>>>(Ntot, rs2, cur2, bsums);
        k_fill2<<<nbH, 256, 0, stream>>>(iu_e, Eiu, ui_e, Eui, cur2, NU, csr2);
        int pairs = (Ntot + 1) / 2;
        k_msg2<<<(pairs + 3) / 4, 256, 0, stream>>>(uf_bf, if_bf, rs2, csr2, x_u, x_i, NU, NI);
        k_gemm7<<<512, 512, 0, stream>>>(x_u, x_i, Wt_u2, Wt_i2, bu, bi, gamma, beta,
                                         NU, NI, out);
        return;
    }

    // ---------- fallback: R2 path (needs ~2.2 MB ws) ----------
    float* u_out = out;
    float* i_out = out + nfU;
    __hip_bfloat16* Wt_u = (__hip_bfloat16*)d_ws;
    __hip_bfloat16* Wt_i = Wt_u + 256 * 256;
    int* deg    = (int*)(Wt_i + 256 * 256);
    int* rs     = deg + Nmax;
    int* bs     = rs + Nmax + 1;
    int* cursor = bs + 1024;
    int* csr    = cursor + Nmax;

    k_wcvt<<<512, 256, 0, stream>>>(Wu, Wi, Wt_u, Wt_i);

    auto run_side = [&](const float* srcf, const float* tgtf, const int* edges, int E,
                        int N, const __hip_bfloat16* Wt, const float* bias, float* y) {
        const int* esrc = edges;
        const int* edst = edges + E;
        hipMemsetAsync(deg, 0, (size_t)N * sizeof(int), stream);
        hipMemsetAsync(cursor, 0, (size_t)N * sizeof(int), stream);
        k_hist<<<(E + 255) / 256, 256, 0, stream>>>(edst, E, deg);
        int nb = (N + 1023) / 1024;
        k_scan_block<<<nb, 1024, 0, stream>>>(deg, N, rs, bs);
        k_scan_sums<<<1, 1024, 0, stream>>>(bs, nb);
        k_finalize_rs<<<(N + 255) / 256, 256, 0, stream>>>(N, rs, bs);
        k_fill<<<(E + 255) / 256, 256, 0, stream>>>(esrc, edst, E, rs, cursor, csr);
        k_msg_x<<<(N + 3) / 4, 256, 0, stream>>>(srcf, tgtf, rs, csr, N, y);
        k_gemm_mfma_ln<<<(N + BM - 1) / BM, 256, 0, stream>>>(y, Wt, bias, gamma, beta, N, y);
    };

    run_side(itf, uf, iu_e, Eiu, NU, Wt_u, bu, u_out);
    run_side(uf, itf, ui_e, Eui, NI, Wt_i, bi, i_out);
}

// Round 14
// 217.682 us; speedup vs baseline: 1.1986x; 1.0345x over previous
//
#include <hip/hip_runtime.h>
#include <hip/hip_bf16.h>

#define D 256
#define BM 64
#define BM2 32    // gemm5 tile rows
#define LDA 264   // LDS k-stride in bf16 elems (528 B rows)
#define LDK 72    // fallback-path pad

typedef __attribute__((ext_vector_type(8))) __bf16 bf16x8;
typedef __attribute__((ext_vector_type(4))) float f32x4;

__device__ __forceinline__ float bf2f(unsigned short u) {
    union { unsigned int i; float f; } c; c.i = ((unsigned int)u) << 16; return c.f;
}
__device__ __forceinline__ float bf2f_lo(unsigned int u) {
    union { unsigned int i; float f; } c; c.i = u << 16; return c.f;
}
__device__ __forceinline__ float bf2f_hi(unsigned int u) {
    union { unsigned int i; float f; } c; c.i = u & 0xffff0000u; return c.f;
}
__device__ __forceinline__ unsigned short f2bf(float f) {
    __hip_bfloat16 h = __float2bfloat16(f);
    return *reinterpret_cast<unsigned short*>(&h);
}
__device__ __forceinline__ unsigned int pack2(float lo, float hi) {
    return (unsigned int)f2bf(lo) | ((unsigned int)f2bf(hi) << 16);
}

// ======================= FAST PATH =======================

// blocks [0,nbF): feat fp32->bf16 ; [nbF,nbF+512): W->Wt[c][k] ; rest: edge histogram.
// deg must be zeroed before this kernel.
__global__ void k_prep(const float* __restrict__ uf, const float* __restrict__ itf,
                       const float* __restrict__ Wu, const float* __restrict__ Wi,
                       unsigned short* __restrict__ feat_bf,
                       unsigned short* __restrict__ Wt_u, unsigned short* __restrict__ Wt_i,
                       const int* __restrict__ iu_e, int Eiu,
                       const int* __restrict__ ui_e, int Eui,
                       int* __restrict__ deg, int NU,
                       size_t nfU, size_t nfTot, int nbF) {
    int b = blockIdx.x;
    if (b < nbF) {
        size_t base = ((size_t)b * 256 + threadIdx.x) * 8;
        if (base < nfTot) {
            const float* s = (base < nfU) ? (uf + base) : (itf + (base - nfU));
            float4 f0 = *(const float4*)s;
            float4 f1 = *(const float4*)(s + 4);
            ushort4 o0, o1;
            o0.x = f2bf(f0.x); o0.y = f2bf(f0.y); o0.z = f2bf(f0.z); o0.w = f2bf(f0.w);
            o1.x = f2bf(f1.x); o1.y = f2bf(f1.y); o1.z = f2bf(f1.z); o1.w = f2bf(f1.w);
            ((ushort4*)(feat_bf + base))[0] = o0;
            ((ushort4*)(feat_bf + base))[1] = o1;
        }
    } else if (b < nbF + 512) {
        int b2 = b - nbF;
        const float* W = (b2 < 256) ? Wu : Wi;
        unsigned short* Wt = (b2 < 256) ? Wt_u : Wt_i;
        int k = b2 & 255;
        int c = threadIdx.x;
        Wt[(size_t)c * 256 + k] = f2bf(W[(size_t)k * 256 + c]);
    } else {
        int e = (b - nbF - 512) * 256 + threadIdx.x;
        if (e < Eiu) {
            atomicAdd(&deg[iu_e[Eiu + e]], 1);
        } else if (e < Eiu + Eui) {
            int e2 = e - Eiu;
            atomicAdd(&deg[NU + ui_e[Eui + e2]], 1);
        }
    }
}

__global__ void k_scan_block(const int* __restrict__ deg, int N,
                             int* __restrict__ rs, int* __restrict__ bsums) {
    __shared__ int s[1024];
    int base = blockIdx.x * 1024;
    int t = threadIdx.x;
    int v = (base + t < N) ? deg[base + t] : 0;
    s[t] = v;
    __syncthreads();
    for (int off = 1; off < 1024; off <<= 1) {
        int add = (t >= off) ? s[t - off] : 0;
        __syncthreads();
        s[t] += add;
        __syncthreads();
    }
    if (base + t < N) rs[base + t + 1] = s[t];
    if (t == 1023) bsums[blockIdx.x] = s[1023];
}

__global__ void k_scan_sums(int* __restrict__ bsums, int nb) {
    __shared__ int s[1024];
    int t = threadIdx.x;
    int v = (t < nb) ? bsums[t] : 0;
    s[t] = v;
    __syncthreads();
    for (int off = 1; off < 1024; off <<= 1) {
        int add = (t >= off) ? s[t - off] : 0;
        __syncthreads();
        s[t] += add;
        __syncthreads();
    }
    if (t < nb) bsums[t] = s[t] - v;
}

__global__ void k_finalize(int N, int* __restrict__ rs, int* __restrict__ cur,
                           const int* __restrict__ bsums) {
    int i = blockIdx.x * blockDim.x + threadIdx.x;
    if (i < N) {
        int v = rs[i + 1] + bsums[i >> 10];
        rs[i + 1] = v;
        cur[i + 1] = v;
    }
    if (i == 0) { rs[0] = 0; cur[0] = 0; }
}

__global__ void k_fill2(const int* __restrict__ iu_e, int Eiu,
                        const int* __restrict__ ui_e, int Eui,
                        int* __restrict__ cur, int NU,
                        int* __restrict__ csr) {
    int e = blockIdx.x * blockDim.x + threadIdx.x;
    if (e < Eiu) {
        int d = iu_e[Eiu + e];
        int p = atomicAdd(&cur[d], 1);
        csr[p] = iu_e[e];
    } else if (e < Eiu + Eui) {
        int e2 = e - Eiu;
        int d = ui_e[Eui + e2];
        int p = atomicAdd(&cur[NU + d], 1);
        csr[p] = ui_e[e2];
    }
}

// x = bf16( tgt + mean(src rows) ); TWO rows per wave (half-wave each),
// 4-unrolled gather -> up to 8 independent row loads in flight. High-occupancy.
__global__ void k_msg2(const unsigned short* __restrict__ uf_bf,
                       const unsigned short* __restrict__ if_bf,
                       const int* __restrict__ rs, const int* __restrict__ csr,
                       unsigned short* __restrict__ x_u, unsigned short* __restrict__ x_i,
                       int NU, int NI) {
    int pair = (blockIdx.x * blockDim.x + threadIdx.x) >> 6;
    int lane = threadIdx.x & 63;
    int half = lane >> 5;
    int hl   = lane & 31;
    int Ntot = NU + NI;
    int wv = pair * 2 + half;
    if (wv >= Ntot) return;

    const unsigned short* src; const unsigned short* tgt; unsigned short* xo; int w;
    if (wv < NU) { src = if_bf; tgt = uf_bf; xo = x_u; w = wv; }
    else         { src = uf_bf; tgt = if_bf; xo = x_i; w = wv - NU; }

    int s0 = rs[wv], s1 = rs[wv + 1];
    float a0[8] = {}, a1[8] = {}, a2[8] = {}, a3[8] = {};

    int i = s0;
    for (; i + 4 <= s1; i += 4) {
        int e0 = csr[i], e1 = csr[i + 1], e2 = csr[i + 2], e3 = csr[i + 3];
        uint4 r0 = ((const uint4*)(src + (size_t)e0 * D))[hl];
        uint4 r1 = ((const uint4*)(src + (size_t)e1 * D))[hl];
        uint4 r2 = ((const uint4*)(src + (size_t)e2 * D))[hl];
        uint4 r3 = ((const uint4*)(src + (size_t)e3 * D))[hl];
        a0[0] += bf2f_lo(r0.x); a0[1] += bf2f_hi(r0.x); a0[2] += bf2f_lo(r0.y); a0[3] += bf2f_hi(r0.y);
        a0[4] += bf2f_lo(r0.z); a0[5] += bf2f_hi(r0.z); a0[6] += bf2f_lo(r0.w); a0[7] += bf2f_hi(r0.w);
        a1[0] += bf2f_lo(r1.x); a1[1] += bf2f_hi(r1.x); a1[2] += bf2f_lo(r1.y); a1[3] += bf2f_hi(r1.y);
        a1[4] += bf2f_lo(r1.z); a1[5] += bf2f_hi(r1.z); a1[6] += bf2f_lo(r1.w); a1[7] += bf2f_hi(r1.w);
        a2[0] += bf2f_lo(r2.x); a2[1] += bf2f_hi(r2.x); a2[2] += bf2f_lo(r2.y); a2[3] += bf2f_hi(r2.y);
        a2[4] += bf2f_lo(r2.z); a2[5] += bf2f_hi(r2.z); a2[6] += bf2f_lo(r2.w); a2[7] += bf2f_hi(r2.w);
        a3[0] += bf2f_lo(r3.x); a3[1] += bf2f_hi(r3.x); a3[2] += bf2f_lo(r3.y); a3[3] += bf2f_hi(r3.y);
        a3[4] += bf2f_lo(r3.z); a3[5] += bf2f_hi(r3.z); a3[6] += bf2f_lo(r3.w); a3[7] += bf2f_hi(r3.w);
    }
    for (; i < s1; ++i) {
        int e0 = csr[i];
        uint4 r0 = ((const uint4*)(src + (size_t)e0 * D))[hl];
        a0[0] += bf2f_lo(r0.x); a0[1] += bf2f_hi(r0.x); a0[2] += bf2f_lo(r0.y); a0[3] += bf2f_hi(r0.y);
        a0[4] += bf2f_lo(r0.z); a0[5] += bf2f_hi(r0.z); a0[6] += bf2f_lo(r0.w); a0[7] += bf2f_hi(r0.w);
    }

    int cnt = s1 - s0;
    float inv = 1.0f / (float)(cnt > 0 ? cnt : 1);
    uint4 tv = ((const uint4*)(tgt + (size_t)w * D))[hl];
    float x0 = bf2f_lo(tv.x) + (a0[0] + a1[0] + a2[0] + a3[0]) * inv;
    float x1 = bf2f_hi(tv.x) + (a0[1] + a1[1] + a2[1] + a3[1]) * inv;
    float x2 = bf2f_lo(tv.y) + (a0[2] + a1[2] + a2[2] + a3[2]) * inv;
    float x3 = bf2f_hi(tv.y) + (a0[3] + a1[3] + a2[3] + a3[3]) * inv;
    float x4 = bf2f_lo(tv.z) + (a0[4] + a1[4] + a2[4] + a3[4]) * inv;
    float x5 = bf2f_hi(tv.z) + (a0[5] + a1[5] + a2[5] + a3[5]) * inv;
    float x6 = bf2f_lo(tv.w) + (a0[6] + a1[6] + a2[6] + a3[6]) * inv;
    float x7 = bf2f_hi(tv.w) + (a0[7] + a1[7] + a2[7] + a3[7]) * inv;
    uint4 o;
    o.x = pack2(x0, x1); o.y = pack2(x2, x3); o.z = pack2(x4, x5); o.w = pack2(x6, x7);
    ((uint4*)(xo + (size_t)w * D))[hl] = o;
}

// ---- GEMM + bias + ReLU + LayerNorm, SMALL-TILE / HIGH-TLP variant (best measured).
// BM2=32 rows per block, 256 threads (4 waves). ~17KB LDS, ~60 VGPR.
// B streamed from L2; scattered stores.
__launch_bounds__(256)
__global__ void k_gemm5(const unsigned short* __restrict__ x_u,
                        const unsigned short* __restrict__ x_i,
                        const unsigned short* __restrict__ Wt_u,
                        const unsigned short* __restrict__ Wt_i,
                        const float* __restrict__ bu, const float* __restrict__ bi,
                        const float* __restrict__ gamma, const float* __restrict__ beta,
                        int NU, int NI, int nbU, float* __restrict__ out) {
    __shared__ __align__(16) __hip_bfloat16 As[BM2][LDA];  // 16896 B
    __shared__ float red_s[BM2][4];                         // 512 B
    __shared__ float red_q[BM2][4];                         // 512 B

    int b = blockIdx.x;
    bool isU = b < nbU;
    const unsigned short* X  = isU ? x_u : x_i;
    const unsigned short* Wt = isU ? Wt_u : Wt_i;
    const float* bias        = isU ? bu : bi;
    float* Y                 = isU ? out : out + (size_t)NU * D;
    int N                    = isU ? NU : NI;
    int row0 = (isU ? b : b - nbU) * BM2;

    int t = threadIdx.x;
    int lane = t & 63;
    int w = t >> 6;
    int l15 = lane & 15;
    int l4 = lane >> 4;

    // ---- stage A once: tile = 32 rows x 32 uint4 = 1024 uint4; 4 per thread.
    //      flat uint4 index f = j*256 + t -> row f>>5, col f&31 (coalesced).
    {
        const uint4* Xg = (const uint4*)&X[(size_t)row0 * D];
        #pragma unroll
        for (int j = 0; j < 4; ++j) {
            int f = j * 256 + t;
            int lr = f >> 5;
            int c = f & 31;
            uint4 v = {0, 0, 0, 0};
            if (row0 + lr < N) v = Xg[(size_t)lr * 32 + c];
            *(uint4*)&As[lr][c * 8] = v;
        }
    }

    f32x4 acc[2][4];
    f32x4 zero = {0.f, 0.f, 0.f, 0.f};
    #pragma unroll
    for (int fr = 0; fr < 2; fr++)
        #pragma unroll
        for (int fc = 0; fc < 4; fc++)
            acc[fr][fc] = zero;

    __syncthreads();

    // ---- GEMM: A from LDS, B straight from L2; no barriers in the loop.
    const uint4* Bg = (const uint4*)Wt;   // Wt[col][k]: uint4 index = col*32 + k/8
    int colB = w * 64 + l15;
    #pragma unroll
    for (int ks8 = 0; ks8 < 8; ++ks8) {
        uint4 bq[4];
        #pragma unroll
        for (int fc = 0; fc < 4; ++fc)
            bq[fc] = Bg[(size_t)(colB + fc * 16) * 32 + ks8 * 4 + l4];
        bf16x8 af[2];
        #pragma unroll
        for (int fr = 0; fr < 2; ++fr)
            af[fr] = *(const bf16x8*)&As[fr * 16 + l15][ks8 * 32 + l4 * 8];
        #pragma unroll
        for (int fr = 0; fr < 2; ++fr)
            #pragma unroll
            for (int fc = 0; fc < 4; ++fc)
                acc[fr][fc] = __builtin_amdgcn_mfma_f32_16x16x32_bf16(
                    af[fr], *(bf16x8*)&bq[fc], acc[fr][fc], 0, 0, 0);
    }

    // ---- epilogue: bias + relu + per-row reduce
    float bias_c[4], gam_c[4], bet_c[4];
    #pragma unroll
    for (int fc = 0; fc < 4; fc++) {
        int col = w * 64 + fc * 16 + l15;
        bias_c[fc] = bias[col];
        gam_c[fc]  = gamma[col];
        bet_c[fc]  = beta[col];
    }

    #pragma unroll
    for (int fr = 0; fr < 2; fr++) {
        #pragma unroll
        for (int r = 0; r < 4; r++) {
            int row = fr * 16 + l4 * 4 + r;
            float s = 0.f, q = 0.f;
            #pragma unroll
            for (int fc = 0; fc < 4; fc++) {
                float v = acc[fr][fc][r] + bias_c[fc];
                v = fmaxf(v, 0.f);
                acc[fr][fc][r] = v;
                s += v;
                q += v * v;
            }
            #pragma unroll
            for (int m = 1; m < 16; m <<= 1) {
                s += __shfl_xor(s, m);
                q += __shfl_xor(q, m);
            }
            if (l15 == 0) { red_s[row][w] = s; red_q[row][w] = q; }
        }
    }
    __syncthreads();

    #pragma unroll
    for (int fr = 0; fr < 2; fr++) {
        #pragma unroll
        for (int r = 0; r < 4; r++) {
            int row = fr * 16 + l4 * 4 + r;
            int grow = row0 + row;
            if (grow >= N) continue;
            float s = red_s[row][0] + red_s[row][1] + red_s[row][2] + red_s[row][3];
            float q = red_q[row][0] + red_q[row][1] + red_q[row][2] + red_q[row][3];
            float mu  = s * (1.0f / 256.0f);
            float var = q * (1.0f / 256.0f) - mu * mu;
            float rstd = rsqrtf(var + 1e-5f);
            #pragma unroll
            for (int fc = 0; fc < 4; fc++) {
                int col = w * 64 + fc * 16 + l15;
                Y[(size_t)grow * D + col] = (acc[fr][fc][r] - mu) * rstd * gam_c[fc] + bet_c[fc];
            }
        }
    }
}

// ======================= FALLBACK PATH (R2, small-ws) =======================

__global__ void k_hist(const int* __restrict__ dst, int E, int* __restrict__ deg) {
    int e = blockIdx.x * blockDim.x + threadIdx.x;
    if (e < E) atomicAdd(&deg[dst[e]], 1);
}

__global__ void k_finalize_rs(int N, int* __restrict__ rs, const int* __restrict__ bsums) {
    int i = blockIdx.x * blockDim.x + threadIdx.x;
    if (i < N) rs[i + 1] += bsums[i >> 10];
    if (i == 0) rs[0] = 0;
}

__global__ void k_fill(const int* __restrict__ src, const int* __restrict__ dst, int E,
                       const int* __restrict__ rs, int* __restrict__ cursor,
                       int* __restrict__ csr) {
    int e = blockIdx.x * blockDim.x + threadIdx.x;
    if (e < E) {
        int d = dst[e];
        int p = atomicAdd(&cursor[d], 1);
        csr[rs[d] + p] = src[e];
    }
}

__global__ void k_msg_x(const float* __restrict__ srcf, const float* __restrict__ tgtf,
                        const int* __restrict__ rs, const int* __restrict__ csr,
                        int N, float* __restrict__ xout) {
    int wave = (blockIdx.x * blockDim.x + threadIdx.x) >> 6;
    int lane = threadIdx.x & 63;
    if (wave >= N) return;
    int s0 = rs[wave], s1 = rs[wave + 1];
    float4 acc = make_float4(0.f, 0.f, 0.f, 0.f);
    for (int i = s0; i < s1; i++) {
        int s = csr[i];
        float4 f = *(const float4*)&srcf[(size_t)s * D + lane * 4];
        acc.x += f.x; acc.y += f.y; acc.z += f.z; acc.w += f.w;
    }
    int cnt = s1 - s0;
    float inv = 1.0f / (float)(cnt > 0 ? cnt : 1);
    float4 t = *(const float4*)&tgtf[(size_t)wave * D + lane * 4];
    float4 x;
    x.x = t.x + acc.x * inv;
    x.y = t.y + acc.y * inv;
    x.z = t.z + acc.z * inv;
    x.w = t.w + acc.w * inv;
    *(float4*)&xout[(size_t)wave * D + lane * 4] = x;
}

__global__ void k_wcvt(const float* __restrict__ W0, const float* __restrict__ W1,
                       __hip_bfloat16* __restrict__ Wt0, __hip_bfloat16* __restrict__ Wt1) {
    int b = blockIdx.x;
    const float* W = (b < 256) ? W0 : W1;
    __hip_bfloat16* Wt = (b < 256) ? Wt0 : Wt1;
    int k = b & 255;
    int c = threadIdx.x;
    Wt[(size_t)c * 256 + k] = __float2bfloat16(W[(size_t)k * 256 + c]);
}

__launch_bounds__(256)
__global__ void k_gemm_mfma_ln(const float* __restrict__ X,
                               const __hip_bfloat16* __restrict__ Wt,
                               const float* __restrict__ bias,
                               const float* __restrict__ gamma,
                               const float* __restrict__ beta,
                               int N, float* __restrict__ Y) {
    __shared__ __hip_bfloat16 As[BM][LDK];
    __shared__ __hip_bfloat16 Bs[D][LDK];
    __shared__ float red_s[BM][4];
    __shared__ float red_q[BM][4];

    int t = threadIdx.x;
    int lane = t & 63;
    int w = t >> 6;
    int l15 = lane & 15;
    int l4 = lane >> 4;
    int row0 = blockIdx.x * BM;

    f32x4 acc[4][4];
    f32x4 zero = {0.f, 0.f, 0.f, 0.f};
    #pragma unroll
    for (int fr = 0; fr < 4; fr++)
        #pragma unroll
        for (int fc = 0; fc < 4; fc++)
            acc[fr][fc] = zero;

    for (int k0 = 0; k0 < D; k0 += 64) {
        {
            int i = t >> 2;
            int kq = (t & 3) * 16;
            int r = row0 + i;
            float4 f[4];
            if (r < N) {
                const float4* p = (const float4*)&X[(size_t)r * D + k0 + kq];
                f[0] = p[0]; f[1] = p[1]; f[2] = p[2]; f[3] = p[3];
            } else {
                float4 z4 = make_float4(0.f, 0.f, 0.f, 0.f);
                f[0] = z4; f[1] = z4; f[2] = z4; f[3] = z4;
            }
            __hip_bfloat16 vb[16];
            #pragma unroll
            for (int q = 0; q < 4; q++) {
                vb[q * 4 + 0] = __float2bfloat16(f[q].x);
                vb[q * 4 + 1] = __float2bfloat16(f[q].y);
                vb[q * 4 + 2] = __float2bfloat16(f[q].z);
                vb[q * 4 + 3] = __float2bfloat16(f[q].w);
            }
            *(uint4*)&As[i][kq]     = *(uint4*)&vb[0];
            *(uint4*)&As[i][kq + 8] = *(uint4*)&vb[8];
        }
        #pragma unroll
        for (int pass = 0; pass < 4; pass++) {
            int c = pass * 64 + (t >> 2);
            int kq = (t & 3) * 16;
            const uint4* p = (const uint4*)&Wt[(size_t)c * D + k0 + kq];
            uint4 b0 = p[0], b1 = p[1];
            *(uint4*)&Bs[c][kq]     = b0;
            *(uint4*)&Bs[c][kq + 8] = b1;
        }
        __syncthreads();

        #pragma unroll
        for (int ks = 0; ks < 2; ks++) {
            bf16x8 af[4], bg[4];
            #pragma unroll
            for (int fr = 0; fr < 4; fr++)
                af[fr] = *(const bf16x8*)&As[fr * 16 + l15][ks * 32 + l4 * 8];
            #pragma unroll
            for (int fc = 0; fc < 4; fc++)
                bg[fc] = *(const bf16x8*)&Bs[w * 64 + fc * 16 + l15][ks * 32 + l4 * 8];
            #pragma unroll
            for (int fr = 0; fr < 4; fr++)
                #pragma unroll
                for (int fc = 0; fc < 4; fc++)
                    acc[fr][fc] = __builtin_amdgcn_mfma_f32_16x16x32_bf16(
                        af[fr], bg[fc], acc[fr][fc], 0, 0, 0);
        }
        __syncthreads();
    }

    float bias_c[4], gam_c[4], bet_c[4];
    #pragma unroll
    for (int fc = 0; fc < 4; fc++) {
        int col = w * 64 + fc * 16 + l15;
        bias_c[fc] = bias[col];
        gam_c[fc]  = gamma[col];
        bet_c[fc]  = beta[col];
    }

    #pragma unroll
    for (int fr = 0; fr < 4; fr++) {
        #pragma unroll
        for (int r = 0; r < 4; r++) {
            int row = fr * 16 + l4 * 4 + r;
            float s = 0.f, q = 0.f;
            #pragma unroll
            for (int fc = 0; fc < 4; fc++) {
                float v = acc[fr][fc][r] + bias_c[fc];
                v = fmaxf(v, 0.f);
                acc[fr][fc][r] = v;
                s += v;
                q += v * v;
            }
            #pragma unroll
            for (int m = 1; m < 16; m <<= 1) {
                s += __shfl_xor(s, m);
                q += __shfl_xor(q, m);
            }
            if (l15 == 0) { red_s[row][w] = s; red_q[row][w] = q; }
        }
    }
    __syncthreads();

    #pragma unroll
    for (int fr = 0; fr < 4; fr++) {
        #pragma unroll
        for (int r = 0; r < 4; r++) {
            int row = fr * 16 + l4 * 4 + r;
            int grow = row0 + row;
            if (grow >= N) continue;
            float s = red_s[row][0] + red_s[row][1] + red_s[row][2] + red_s[row][3];
            float q = red_q[row][0] + red_q[row][1] + red_q[row][2] + red_q[row][3];
            float mu  = s * (1.0f / 256.0f);
            float var = q * (1.0f / 256.0f) - mu * mu;
            float rstd = rsqrtf(var + 1e-5f);
            #pragma unroll
            for (int fc = 0; fc < 4; fc++) {
                int col = w * 64 + fc * 16 + l15;
                Y[(size_t)grow * D + col] = (acc[fr][fc][r] - mu) * rstd * gam_c[fc] + bet_c[fc];
            }
        }
    }
}

// ======================= launch =======================

extern "C" void kernel_launch(void* const* d_in, const int* in_sizes, int n_in,
                              void* d_out, int out_size, void* d_ws, size_t ws_size,
                              hipStream_t stream) {
    const float* uf    = (const float*)d_in[0];
    const float* itf   = (const float*)d_in[1];
    const int*   ui_e  = (const int*)d_in[2];   // [2, Eui] user->item
    const int*   iu_e  = (const int*)d_in[3];   // [2, Eiu] item->user
    const float* Wu    = (const float*)d_in[4];
    const float* bu    = (const float*)d_in[5];
    const float* Wi    = (const float*)d_in[6];
    const float* bi    = (const float*)d_in[7];
    const float* gamma = (const float*)d_in[8];
    const float* beta  = (const float*)d_in[9];

    int NU  = in_sizes[0] / D;
    int NI  = in_sizes[1] / D;
    int Eui = in_sizes[2] / 2;
    int Eiu = in_sizes[3] / 2;
    int Nmax = NU > NI ? NU : NI;
    int Ntot = NU + NI;
    int Etot = Eiu + Eui;

    float* out   = (float*)d_out;
    size_t nfU = (size_t)NU * D;
    size_t nfI = (size_t)NI * D;
    size_t nfTot = nfU + nfI;

    // fast-path ws layout
    unsigned short* uf_bf = (unsigned short*)d_ws;     // nfU
    unsigned short* if_bf = uf_bf + nfU;               // nfI
    unsigned short* x_u   = if_bf + nfI;               // nfU
    unsigned short* x_i   = x_u + nfU;                 // nfI
    unsigned short* Wt_u2 = x_i + nfI;                 // 65536
    unsigned short* Wt_i2 = Wt_u2 + 65536;             // 65536
    int* deg2  = (int*)(Wt_i2 + 65536);                // Ntot
    int* rs2   = deg2 + Ntot;                          // Ntot+1
    int* cur2  = rs2 + Ntot + 1;                       // Ntot+1
    int* bsums = cur2 + Ntot + 1;                      // 1024
    int* csr2  = bsums + 1024;                         // Etot
    size_t needed = (size_t)((char*)(csr2 + Etot) - (char*)d_ws);

    if (ws_size >= needed) {
        int nbF = (int)((nfTot + 2047) / 2048);
        int nbH = (Etot + 255) / 256;
        hipMemsetAsync(deg2, 0, (size_t)Ntot * sizeof(int), stream);
        k_prep<<<nbF + 512 + nbH, 256, 0, stream>>>(uf, itf, Wu, Wi, uf_bf, Wt_u2, Wt_i2,
                                                    iu_e, Eiu, ui_e, Eui, deg2, NU,
                                                    nfU, nfTot, nbF);
        int nb = (Ntot + 1023) / 1024;
        k_scan_block<<<nb, 1024, 0, stream>>>(deg2, Ntot, rs2, bsums);
        k_scan_sums<<<1, 1024, 0, stream>>>(bsums, nb);
        k_finalize<<<(Ntot + 255) / 256, 256, 0, stream>>>(Ntot, rs2, cur2, bsums);
        k_fill2<<<nbH, 256, 0, stream>>>(iu_e, Eiu, ui_e, Eui, cur2, NU, csr2);
        int pairs = (Ntot + 1) / 2;
        k_msg2<<<(pairs + 3) / 4, 256, 0, stream>>>(uf_bf, if_bf, rs2, csr2, x_u, x_i, NU, NI);
        int nbU = (NU + BM2 - 1) / BM2;
        int nbI = (NI + BM2 - 1) / BM2;
        k_gemm5<<<nbU + nbI, 256, 0, stream>>>(x_u, x_i, Wt_u2, Wt_i2, bu, bi, gamma, beta,
                                               NU, NI, nbU, out);
        return;
    }

    // ---------- fallback: R2 path (needs ~2.2 MB ws) ----------
    float* u_out = out;
    float* i_out = out + nfU;
    __hip_bfloat16* Wt_u = (__hip_bfloat16*)d_ws;
    __hip_bfloat16* Wt_i = Wt_u + 256 * 256;
    int* deg    = (int*)(Wt_i + 256 * 256);
    int* rs     = deg + Nmax;
    int* bs     = rs + Nmax + 1;
    int* cursor = bs + 1024;
    int* csr    = cursor + Nmax;

    k_wcvt<<<512, 256, 0, stream>>>(Wu, Wi, Wt_u, Wt_i);

    auto run_side = [&](const float* srcf, const float* tgtf, const int* edges, int E,
                        int N, const __hip_bfloat16* Wt, const float* bias, float* y) {
        const int* esrc = edges;
        const int* edst = edges + E;
        hipMemsetAsync(deg, 0, (size_t)N * sizeof(int), stream);
        hipMemsetAsync(cursor, 0, (size_t)N * sizeof(int), stream);
        k_hist<<<(E + 255) / 256, 256, 0, stream>>>(edst, E, deg);
        int nb = (N + 1023) / 1024;
        k_scan_block<<<nb, 1024, 0, stream>>>(deg, N, rs, bs);
        k_scan_sums<<<1, 1024, 0, stream>>>(bs, nb);
        k_finalize_rs<<<(N + 255) / 256, 256, 0, stream>>>(N, rs, bs);
        k_fill<<<(E + 255) / 256, 256, 0, stream>>>(esrc, edst, E, rs, cursor, csr);
        k_msg_x<<<(N + 3) / 4, 256, 0, stream>>>(srcf, tgtf, rs, csr, N, y);
        k_gemm_mfma_ln<<<(N + BM - 1) / BM, 256, 0, stream>>>(y, Wt, bias, gamma, beta, N, y);
    };

    run_side(itf, uf, iu_e, Eiu, NU, Wt_u, bu, u_out);
    run_side(uf, itf, ui_e, Eui, NI, Wt_i, bi, i_out);
}